// Round 1
// baseline (949.196 us; speedup 1.0000x reference)
//
#include <hip/hip_runtime.h>
#include <hip/hip_bf16.h>
#include <math.h>

typedef __bf16 bf16_t;
typedef bf16_t bf16x8 __attribute__((ext_vector_type(8)));
typedef bf16_t bf16x4 __attribute__((ext_vector_type(4)));
typedef float  f32x4  __attribute__((ext_vector_type(4)));

#define D_IN   512
#define DMODEL 1024
#define SEQ    2048
#define BATCH  8
#define NTOK   (BATCH*SEQ)

typedef __attribute__((address_space(1))) unsigned int gu32;
typedef __attribute__((address_space(3))) unsigned int lu32;

__device__ __forceinline__ void async16(const void* g, void* l) {
    __builtin_amdgcn_global_load_lds((gu32*)g, (lu32*)l, 16, 0, 0);
}

// ---------------------------------------------------------------------------
// Unified bf16 GEMM: C[M,N] = A[M,K] * B[N,K]^T   (both row-major over K)
// 128x128 block tile, 4 waves, each wave 64x64 (4x4 grid of 16x16x32 MFMA).
// EPI: 0 = +bias[n] + pos_enc[m%SEQ][n]          (embed)
//      1 = +bias[n]                              (Q, K)
//      2 = +bias[n], write transposed -> VT[b][n][s]   (V)
//      3 = *1/32                                 (scores)
//      4 = +resid[m][n]                          (P*V + x -> h)
//      5 = logits[m] += sum_n tanh(C)*sq[n]      (soft_key, no C write)
// ---------------------------------------------------------------------------
template<int EPI>
__global__ __launch_bounds__(256)
void gemm_bt(const bf16_t* __restrict__ Ab, const bf16_t* __restrict__ Bb,
             bf16_t* __restrict__ Cb, int K, int ldc,
             long batchA, long batchB, long batchC,
             const float* __restrict__ bias, const float* __restrict__ aux_f,
             const bf16_t* __restrict__ resid, float* __restrict__ logits)
{
    __shared__ __align__(16) bf16_t As[128*32];
    __shared__ __align__(16) bf16_t Bs[128*32];

    const int tid  = threadIdx.x;
    const int lane = tid & 63;
    const int wave = tid >> 6;
    const int z    = blockIdx.z;

    const bf16_t* A  = Ab + (long)z * batchA;
    const bf16_t* Bp = Bb + (long)z * batchB;
    const int mtile = blockIdx.y * 128;
    const int ntile = blockIdx.x * 128;

    f32x4 acc[4][4];
    #pragma unroll
    for (int i = 0; i < 4; ++i)
        #pragma unroll
        for (int j = 0; j < 4; ++j)
            acc[i][j] = (f32x4)(0.f);

    const int lr = lane & 15;          // fragment col / row-in-tile
    const int lq = lane >> 4;          // quad 0..3
    const int wrow = (wave >> 1) * 64;
    const int wcol = (wave & 1) * 64;

    const int srow = lane >> 2;        // staging: 0..15
    const int skq  = (lane & 3) * 8;   // staging: k offset 0/8/16/24

    for (int k0 = 0; k0 < K; k0 += 32) {
        __syncthreads();               // previous iter's LDS reads done
        #pragma unroll
        for (int j = 0; j < 2; ++j) {
            const int chunk = (wave << 1) + j;        // 0..7
            const int row   = (chunk << 4) + srow;    // 0..127
            async16(A  + (long)(mtile + row) * K + (k0 + skq), &As[chunk << 9]);
            async16(Bp + (long)(ntile + row) * K + (k0 + skq), &Bs[chunk << 9]);
        }
        __syncthreads();               // drains vmcnt (global_load_lds) too

        bf16x8 af[4], bf[4];
        #pragma unroll
        for (int t = 0; t < 4; ++t)
            af[t] = *(const bf16x8*)&As[(wrow + t*16 + lr)*32 + lq*8];
        #pragma unroll
        for (int t = 0; t < 4; ++t)
            bf[t] = *(const bf16x8*)&Bs[(wcol + t*16 + lr)*32 + lq*8];
        #pragma unroll
        for (int tr = 0; tr < 4; ++tr)
            #pragma unroll
            for (int tc = 0; tc < 4; ++tc)
                acc[tr][tc] = __builtin_amdgcn_mfma_f32_16x16x32_bf16(
                                  af[tr], bf[tc], acc[tr][tc], 0, 0, 0);
    }

    // epilogue: C/D layout n = lane&15, m = (lane>>4)*4 + reg  [m89-verified]
    bf16_t* C = Cb + (long)z * batchC;
    const int mbase = mtile + wrow + lq*4;
    #pragma unroll
    for (int tr = 0; tr < 4; ++tr) {
        #pragma unroll
        for (int reg = 0; reg < 4; ++reg) {
            const int m = mbase + tr*16 + reg;
            if constexpr (EPI == 5) {
                float rs = 0.f;
                #pragma unroll
                for (int tc = 0; tc < 4; ++tc) {
                    const int n = ntile + wcol + tc*16 + lr;
                    rs += tanhf(acc[tr][tc][reg]) * aux_f[n];
                }
                rs += __shfl_xor(rs, 1);
                rs += __shfl_xor(rs, 2);
                rs += __shfl_xor(rs, 4);
                rs += __shfl_xor(rs, 8);
                if (lr == 0) atomicAdd(&logits[m], rs);
            } else {
                #pragma unroll
                for (int tc = 0; tc < 4; ++tc) {
                    const int n = ntile + wcol + tc*16 + lr;
                    float v = acc[tr][tc][reg];
                    if constexpr (EPI == 0) v += bias[n] + aux_f[(m & (SEQ-1))*DMODEL + n];
                    if constexpr (EPI == 1 || EPI == 2) v += bias[n];
                    if constexpr (EPI == 3) v *= 0.03125f;   // 1/sqrt(1024)
                    if constexpr (EPI == 4) v += (float)resid[(long)z*batchC + (long)m*ldc + n];
                    if constexpr (EPI == 2) {
                        // V transposed: VT[b][n][s], b = m/SEQ, s = m%SEQ
                        Cb[((long)(m >> 11)*DMODEL + n)*SEQ + (m & (SEQ-1))] = (bf16_t)v;
                    } else {
                        C[(long)m*ldc + n] = (bf16_t)v;
                    }
                }
            }
        }
    }
}

// ---------------------------------------------------------------------------
__global__ void cast_f32_bf16(const float* __restrict__ s, bf16_t* __restrict__ d, int n4) {
    int i = blockIdx.x*256 + threadIdx.x;
    if (i < n4) {
        const float4 f = ((const float4*)s)[i];
        bf16x4 o;
        o.x = (bf16_t)f.x; o.y = (bf16_t)f.y; o.z = (bf16_t)f.z; o.w = (bf16_t)f.w;
        ((bf16x4*)d)[i] = o;
    }
}

__global__ void zero_f32_k(float* __restrict__ p, int n) {
    int i = blockIdx.x*256 + threadIdx.x;
    if (i < n) p[i] = 0.f;
}

// row softmax over 2048 bf16, in place; one block per row
__global__ __launch_bounds__(256) void softmax_rows_bf16(bf16_t* __restrict__ P) {
    bf16_t* row = P + (long)blockIdx.x * SEQ;
    const int t = threadIdx.x, lane = t & 63, wave = t >> 6;
    __shared__ float sm[8];
    float v[8]; float mx = -3.0e38f;
    #pragma unroll
    for (int j = 0; j < 8; ++j) { v[j] = (float)row[t + 256*j]; mx = fmaxf(mx, v[j]); }
    #pragma unroll
    for (int o = 32; o; o >>= 1) mx = fmaxf(mx, __shfl_xor(mx, o));
    if (lane == 0) sm[wave] = mx;
    __syncthreads();
    mx = fmaxf(fmaxf(sm[0], sm[1]), fmaxf(sm[2], sm[3]));
    float s = 0.f;
    #pragma unroll
    for (int j = 0; j < 8; ++j) { v[j] = __expf(v[j] - mx); s += v[j]; }
    #pragma unroll
    for (int o = 32; o; o >>= 1) s += __shfl_xor(s, o);
    if (lane == 0) sm[4 + wave] = s;
    __syncthreads();
    s = (sm[4] + sm[5]) + (sm[6] + sm[7]);
    const float inv = 1.f / s;
    #pragma unroll
    for (int j = 0; j < 8; ++j) row[t + 256*j] = (bf16_t)(v[j] * inv);
}

// per-batch softmax over 2048 fp32 logits
__global__ __launch_bounds__(256) void softmax_vec(const float* __restrict__ L, float* __restrict__ W) {
    const float* l = L + (long)blockIdx.x * SEQ;
    float* w = W + (long)blockIdx.x * SEQ;
    const int t = threadIdx.x, lane = t & 63, wave = t >> 6;
    __shared__ float sm[8];
    float v[8]; float mx = -3.0e38f;
    #pragma unroll
    for (int j = 0; j < 8; ++j) { v[j] = l[t + 256*j]; mx = fmaxf(mx, v[j]); }
    #pragma unroll
    for (int o = 32; o; o >>= 1) mx = fmaxf(mx, __shfl_xor(mx, o));
    if (lane == 0) sm[wave] = mx;
    __syncthreads();
    mx = fmaxf(fmaxf(sm[0], sm[1]), fmaxf(sm[2], sm[3]));
    float s = 0.f;
    #pragma unroll
    for (int j = 0; j < 8; ++j) { v[j] = __expf(v[j] - mx); s += v[j]; }
    #pragma unroll
    for (int o = 32; o; o >>= 1) s += __shfl_xor(s, o);
    if (lane == 0) sm[4 + wave] = s;
    __syncthreads();
    s = (sm[4] + sm[5]) + (sm[6] + sm[7]);
    const float inv = 1.f / s;
    #pragma unroll
    for (int j = 0; j < 8; ++j) w[t + 256*j] = v[j] * inv;
}

// LayerNorm over 1024: one block per row, h bf16 -> H bf16
__global__ __launch_bounds__(256) void layernorm_k(const bf16_t* __restrict__ h, bf16_t* __restrict__ H,
                                                   const float* __restrict__ gam, const float* __restrict__ bet) {
    const long row = blockIdx.x;
    const bf16_t* hr = h + row*DMODEL;
    bf16_t* Hr = H + row*DMODEL;
    const int t = threadIdx.x, lane = t & 63, wave = t >> 6;
    __shared__ float sm[8];
    float v[4]; float s = 0.f, q = 0.f;
    #pragma unroll
    for (int j = 0; j < 4; ++j) { v[j] = (float)hr[t + 256*j]; s += v[j]; q += v[j]*v[j]; }
    #pragma unroll
    for (int o = 32; o; o >>= 1) { s += __shfl_xor(s, o); q += __shfl_xor(q, o); }
    if (lane == 0) { sm[wave] = s; sm[4 + wave] = q; }
    __syncthreads();
    s = (sm[0] + sm[1]) + (sm[2] + sm[3]);
    q = (sm[4] + sm[5]) + (sm[6] + sm[7]);
    const float mu  = s * (1.f/DMODEL);
    const float var = q * (1.f/DMODEL) - mu*mu;
    const float r   = rsqrtf(var + 1e-5f);
    #pragma unroll
    for (int j = 0; j < 4; ++j) {
        const int n = t + 256*j;
        Hr[n] = (bf16_t)((v[j] - mu)*r*gam[n] + bet[n]);
    }
}

// out[b][o] = sum_s w[b][s] * H[b][s][o]; grid (8 o-tiles, 8 batches)
__global__ __launch_bounds__(256) void final_out(const float* __restrict__ w,
                                                 const bf16_t* __restrict__ H,
                                                 float* __restrict__ out) {
    const int b = blockIdx.y;
    const int o = blockIdx.x*128 + (threadIdx.x & 127);
    const int half = threadIdx.x >> 7;
    const bf16_t* Hb = H + (long)b * SEQ * DMODEL;
    const float*  wb = w + b * SEQ;
    float s = 0.f;
    for (int i = half*1024; i < (half+1)*1024; ++i)
        s += wb[i] * (float)Hb[(long)i*DMODEL + o];
    __shared__ float buf[128];
    if (half) buf[threadIdx.x & 127] = s;
    __syncthreads();
    if (!half) out[b*DMODEL + o] = s + buf[threadIdx.x & 127];
}

// ---------------------------------------------------------------------------
extern "C" void kernel_launch(void* const* d_in, const int* in_sizes, int n_in,
                              void* d_out, int out_size, void* d_ws, size_t ws_size,
                              hipStream_t stream) {
    (void)in_sizes; (void)n_in; (void)out_size; (void)ws_size;
    const float* inp = (const float*)d_in[0];
    const float* emw = (const float*)d_in[1];
    const float* emb = (const float*)d_in[2];
    const float* wqw = (const float*)d_in[3];
    const float* wqb = (const float*)d_in[4];
    const float* wkw = (const float*)d_in[5];
    const float* wkb = (const float*)d_in[6];
    const float* wvw = (const float*)d_in[7];
    const float* wvb = (const float*)d_in[8];
    const float* lng = (const float*)d_in[9];
    const float* lnb = (const float*)d_in[10];
    const float* skw = (const float*)d_in[11];
    const float* sq  = (const float*)d_in[12];
    const float* pos = (const float*)d_in[13];
    float* out = (float*)d_out;

    char* ws = (char*)d_ws;
    bf16_t* in_b   = (bf16_t*)(ws + 0);            // 16 MB
    bf16_t* we_b   = (bf16_t*)(ws + 16777216);     // 1 MB
    bf16_t* wq_b   = (bf16_t*)(ws + 17825792);     // 2 MB
    bf16_t* wk_b   = (bf16_t*)(ws + 19922944);     // 2 MB
    bf16_t* wv_b   = (bf16_t*)(ws + 22020096);     // 2 MB
    bf16_t* sk_b   = (bf16_t*)(ws + 24117248);     // 2 MB
    float*  logits = (float*)(ws + 26214400);      // 64 KB
    float*  wsoft  = (float*)(ws + 26279936);      // 64 KB
    bf16_t* xb     = (bf16_t*)(ws + 26345472);     // 32 MB  x (bf16)
    bf16_t* Qb     = (bf16_t*)(ws + 59899904);     // 32 MB  Q, later h
    bf16_t* Kb     = (bf16_t*)(ws + 93454336);     // 32 MB
    bf16_t* VT     = (bf16_t*)(ws + 127008768);    // 32 MB  V^T per batch [1024][2048]
    bf16_t* Hb     = (bf16_t*)(ws + 160563200);    // 32 MB
    bf16_t* Pb     = (bf16_t*)(ws + 194117632);    // 64 MB  scores/probs

    // casts fp32 -> bf16
    cast_f32_bf16<<<8192, 256, 0, stream>>>(inp, in_b, 2097152);
    cast_f32_bf16<<<512,  256, 0, stream>>>(emw, we_b, 131072);
    cast_f32_bf16<<<1024, 256, 0, stream>>>(wqw, wq_b, 262144);
    cast_f32_bf16<<<1024, 256, 0, stream>>>(wkw, wk_b, 262144);
    cast_f32_bf16<<<1024, 256, 0, stream>>>(wvw, wv_b, 262144);
    cast_f32_bf16<<<1024, 256, 0, stream>>>(skw, sk_b, 262144);
    zero_f32_k<<<64, 256, 0, stream>>>(logits, NTOK);

    // x = inputs @ embed_w^T + bias + pos
    gemm_bt<0><<<dim3(8, 128, 1), 256, 0, stream>>>(in_b, we_b, xb, D_IN, DMODEL,
        0, 0, 0, emb, pos, nullptr, nullptr);
    // Q, K, V
    gemm_bt<1><<<dim3(8, 128, 1), 256, 0, stream>>>(xb, wq_b, Qb, DMODEL, DMODEL,
        0, 0, 0, wqb, nullptr, nullptr, nullptr);
    gemm_bt<1><<<dim3(8, 128, 1), 256, 0, stream>>>(xb, wk_b, Kb, DMODEL, DMODEL,
        0, 0, 0, wkb, nullptr, nullptr, nullptr);
    gemm_bt<2><<<dim3(8, 128, 1), 256, 0, stream>>>(xb, wv_b, VT, DMODEL, 0,
        0, 0, 0, wvb, nullptr, nullptr, nullptr);
    // S = Q K^T / 32 (per batch), bf16
    gemm_bt<3><<<dim3(16, 16, BATCH), 256, 0, stream>>>(Qb, Kb, Pb, DMODEL, SEQ,
        (long)SEQ*DMODEL, (long)SEQ*DMODEL, (long)SEQ*SEQ, nullptr, nullptr, nullptr, nullptr);
    softmax_rows_bf16<<<NTOK, 256, 0, stream>>>(Pb);
    // h = P V + x  (written over Q buffer)
    gemm_bt<4><<<dim3(8, 16, BATCH), 256, 0, stream>>>(Pb, VT, Qb, SEQ, DMODEL,
        (long)SEQ*SEQ, (long)DMODEL*SEQ, (long)SEQ*DMODEL, nullptr, nullptr, xb, nullptr);
    layernorm_k<<<NTOK, 256, 0, stream>>>(Qb, Hb, lng, lnb);
    // logits[m] = sum_n tanh(H skw^T) * soft_query[n]
    gemm_bt<5><<<dim3(8, 128, 1), 256, 0, stream>>>(Hb, sk_b, nullptr, DMODEL, 0,
        0, 0, 0, nullptr, sq, nullptr, logits);
    softmax_vec<<<BATCH, 256, 0, stream>>>(logits, wsoft);
    final_out<<<dim3(8, BATCH), 256, 0, stream>>>(wsoft, Hb, out);
}

// Round 2
// 687.879 us; speedup vs baseline: 1.3799x; 1.3799x over previous
//
#include <hip/hip_runtime.h>
#include <hip/hip_bf16.h>
#include <math.h>

typedef __bf16 bf16_t;
typedef bf16_t bf16x8 __attribute__((ext_vector_type(8)));
typedef bf16_t bf16x4 __attribute__((ext_vector_type(4)));
typedef float  f32x4  __attribute__((ext_vector_type(4)));

#define D_IN   512
#define DMODEL 1024
#define SEQ    2048
#define BATCH  8
#define NTOK   (BATCH*SEQ)

typedef __attribute__((address_space(1))) unsigned int gu32;
typedef __attribute__((address_space(3))) unsigned int lu32;

__device__ __forceinline__ void async16(const void* g, void* l) {
    __builtin_amdgcn_global_load_lds((gu32*)g, (lu32*)l, 16, 0, 0);
}

// ---------------------------------------------------------------------------
// Unified bf16 GEMM: C[M,N] = A[M,K] * B[N,K]^T   (both row-major over K)
// 128x128 block tile, 4 waves, each wave 64x64 (4x4 grid of 16x16x32 MFMA).
// EPI: 0 = +bias[n] + pos_enc[m%SEQ][n]          (embed)
//      1 = +bias[n]                              (Q, K)
//      2 = +bias[n], write transposed -> VT[b][n][s]   (V)
//      3 = *1/32                                 (scores)
//      4 = +resid[m][n]                          (P*V + x -> h)
//      5 = logits[m] += sum_n tanh(C)*sq[n]      (soft_key, no C write)
// ---------------------------------------------------------------------------
template<int EPI>
__global__ __launch_bounds__(256)
void gemm_bt(const bf16_t* __restrict__ Ab, const bf16_t* __restrict__ Bb,
             bf16_t* __restrict__ Cb, int K, int ldc,
             long batchA, long batchB, long batchC,
             const float* __restrict__ bias, const float* __restrict__ aux_f,
             const bf16_t* __restrict__ resid, float* __restrict__ logits)
{
    __shared__ __align__(16) bf16_t As[128*32];
    __shared__ __align__(16) bf16_t Bs[128*32];

    const int tid  = threadIdx.x;
    const int lane = tid & 63;
    const int wave = tid >> 6;
    const int z    = blockIdx.z;

    const bf16_t* A  = Ab + (long)z * batchA;
    const bf16_t* Bp = Bb + (long)z * batchB;
    const int mtile = blockIdx.y * 128;
    const int ntile = blockIdx.x * 128;

    f32x4 acc[4][4];
    #pragma unroll
    for (int i = 0; i < 4; ++i)
        #pragma unroll
        for (int j = 0; j < 4; ++j)
            acc[i][j] = (f32x4)(0.f);

    const int lr = lane & 15;          // fragment col / row-in-tile
    const int lq = lane >> 4;          // quad 0..3
    const int wrow = (wave >> 1) * 64;
    const int wcol = (wave & 1) * 64;

    const int srow = lane >> 2;        // staging: 0..15
    const int skq  = (lane & 3) * 8;   // staging: k offset 0/8/16/24

    for (int k0 = 0; k0 < K; k0 += 32) {
        __syncthreads();               // previous iter's LDS reads done
        #pragma unroll
        for (int j = 0; j < 2; ++j) {
            const int chunk = (wave << 1) + j;        // 0..7
            const int row   = (chunk << 4) + srow;    // 0..127
            async16(A  + (long)(mtile + row) * K + (k0 + skq), &As[chunk << 9]);
            async16(Bp + (long)(ntile + row) * K + (k0 + skq), &Bs[chunk << 9]);
        }
        __syncthreads();               // drains vmcnt (global_load_lds) too

        bf16x8 af[4], bf[4];
        #pragma unroll
        for (int t = 0; t < 4; ++t)
            af[t] = *(const bf16x8*)&As[(wrow + t*16 + lr)*32 + lq*8];
        #pragma unroll
        for (int t = 0; t < 4; ++t)
            bf[t] = *(const bf16x8*)&Bs[(wcol + t*16 + lr)*32 + lq*8];
        #pragma unroll
        for (int tr = 0; tr < 4; ++tr)
            #pragma unroll
            for (int tc = 0; tc < 4; ++tc)
                acc[tr][tc] = __builtin_amdgcn_mfma_f32_16x16x32_bf16(
                                  af[tr], bf[tc], acc[tr][tc], 0, 0, 0);
    }

    // epilogue: C/D layout n = lane&15, m = (lane>>4)*4 + reg  [m89-verified]
    bf16_t* C = Cb + (long)z * batchC;
    const int mbase = mtile + wrow + lq*4;
    #pragma unroll
    for (int tr = 0; tr < 4; ++tr) {
        #pragma unroll
        for (int reg = 0; reg < 4; ++reg) {
            const int m = mbase + tr*16 + reg;
            if constexpr (EPI == 5) {
                float rs = 0.f;
                #pragma unroll
                for (int tc = 0; tc < 4; ++tc) {
                    const int n = ntile + wcol + tc*16 + lr;
                    rs += tanhf(acc[tr][tc][reg]) * aux_f[n];
                }
                rs += __shfl_xor(rs, 1);
                rs += __shfl_xor(rs, 2);
                rs += __shfl_xor(rs, 4);
                rs += __shfl_xor(rs, 8);
                if (lr == 0) atomicAdd(&logits[m], rs);
            } else {
                #pragma unroll
                for (int tc = 0; tc < 4; ++tc) {
                    const int n = ntile + wcol + tc*16 + lr;
                    float v = acc[tr][tc][reg];
                    if constexpr (EPI == 0) v += bias[n] + aux_f[(m & (SEQ-1))*DMODEL + n];
                    if constexpr (EPI == 1 || EPI == 2) v += bias[n];
                    if constexpr (EPI == 3) v *= 0.03125f;   // 1/sqrt(1024)
                    if constexpr (EPI == 4) v += (float)resid[(long)z*batchC + (long)m*ldc + n];
                    if constexpr (EPI == 2) {
                        // V transposed: VT[b][n][s], b = m/SEQ, s = m%SEQ
                        Cb[((long)(m >> 11)*DMODEL + n)*SEQ + (m & (SEQ-1))] = (bf16_t)v;
                    } else {
                        C[(long)m*ldc + n] = (bf16_t)v;
                    }
                }
            }
        }
    }
}

// ---------------------------------------------------------------------------
__global__ void cast_f32_bf16(const float* __restrict__ s, bf16_t* __restrict__ d, int n4) {
    int i = blockIdx.x*256 + threadIdx.x;
    if (i < n4) {
        const float4 f = ((const float4*)s)[i];
        bf16x4 o;
        o.x = (bf16_t)f.x; o.y = (bf16_t)f.y; o.z = (bf16_t)f.z; o.w = (bf16_t)f.w;
        ((bf16x4*)d)[i] = o;
    }
}

__global__ void zero_f32_k(float* __restrict__ p, int n) {
    int i = blockIdx.x*256 + threadIdx.x;
    if (i < n) p[i] = 0.f;
}

// row softmax over 2048 bf16, in place; one block per row
__global__ __launch_bounds__(256) void softmax_rows_bf16(bf16_t* __restrict__ P) {
    bf16_t* row = P + (long)blockIdx.x * SEQ;
    const int t = threadIdx.x, lane = t & 63, wave = t >> 6;
    __shared__ float sm[8];
    float v[8]; float mx = -3.0e38f;
    #pragma unroll
    for (int j = 0; j < 8; ++j) { v[j] = (float)row[t + 256*j]; mx = fmaxf(mx, v[j]); }
    #pragma unroll
    for (int o = 32; o; o >>= 1) mx = fmaxf(mx, __shfl_xor(mx, o));
    if (lane == 0) sm[wave] = mx;
    __syncthreads();
    mx = fmaxf(fmaxf(sm[0], sm[1]), fmaxf(sm[2], sm[3]));
    float s = 0.f;
    #pragma unroll
    for (int j = 0; j < 8; ++j) { v[j] = __expf(v[j] - mx); s += v[j]; }
    #pragma unroll
    for (int o = 32; o; o >>= 1) s += __shfl_xor(s, o);
    if (lane == 0) sm[4 + wave] = s;
    __syncthreads();
    s = (sm[4] + sm[5]) + (sm[6] + sm[7]);
    const float inv = 1.f / s;
    #pragma unroll
    for (int j = 0; j < 8; ++j) row[t + 256*j] = (bf16_t)(v[j] * inv);
}

// per-batch softmax over 2048 fp32 logits
__global__ __launch_bounds__(256) void softmax_vec(const float* __restrict__ L, float* __restrict__ W) {
    const float* l = L + (long)blockIdx.x * SEQ;
    float* w = W + (long)blockIdx.x * SEQ;
    const int t = threadIdx.x, lane = t & 63, wave = t >> 6;
    __shared__ float sm[8];
    float v[8]; float mx = -3.0e38f;
    #pragma unroll
    for (int j = 0; j < 8; ++j) { v[j] = l[t + 256*j]; mx = fmaxf(mx, v[j]); }
    #pragma unroll
    for (int o = 32; o; o >>= 1) mx = fmaxf(mx, __shfl_xor(mx, o));
    if (lane == 0) sm[wave] = mx;
    __syncthreads();
    mx = fmaxf(fmaxf(sm[0], sm[1]), fmaxf(sm[2], sm[3]));
    float s = 0.f;
    #pragma unroll
    for (int j = 0; j < 8; ++j) { v[j] = __expf(v[j] - mx); s += v[j]; }
    #pragma unroll
    for (int o = 32; o; o >>= 1) s += __shfl_xor(s, o);
    if (lane == 0) sm[4 + wave] = s;
    __syncthreads();
    s = (sm[4] + sm[5]) + (sm[6] + sm[7]);
    const float inv = 1.f / s;
    #pragma unroll
    for (int j = 0; j < 8; ++j) w[t + 256*j] = v[j] * inv;
}

// LayerNorm over 1024: one block per row, h bf16 -> H bf16
__global__ __launch_bounds__(256) void layernorm_k(const bf16_t* __restrict__ h, bf16_t* __restrict__ H,
                                                   const float* __restrict__ gam, const float* __restrict__ bet) {
    const long row = blockIdx.x;
    const bf16_t* hr = h + row*DMODEL;
    bf16_t* Hr = H + row*DMODEL;
    const int t = threadIdx.x, lane = t & 63, wave = t >> 6;
    __shared__ float sm[8];
    float v[4]; float s = 0.f, q = 0.f;
    #pragma unroll
    for (int j = 0; j < 4; ++j) { v[j] = (float)hr[t + 256*j]; s += v[j]; q += v[j]*v[j]; }
    #pragma unroll
    for (int o = 32; o; o >>= 1) { s += __shfl_xor(s, o); q += __shfl_xor(q, o); }
    if (lane == 0) { sm[wave] = s; sm[4 + wave] = q; }
    __syncthreads();
    s = (sm[0] + sm[1]) + (sm[2] + sm[3]);
    q = (sm[4] + sm[5]) + (sm[6] + sm[7]);
    const float mu  = s * (1.f/DMODEL);
    const float var = q * (1.f/DMODEL) - mu*mu;
    const float r   = rsqrtf(var + 1e-5f);
    #pragma unroll
    for (int j = 0; j < 4; ++j) {
        const int n = t + 256*j;
        Hr[n] = (bf16_t)((v[j] - mu)*r*gam[n] + bet[n]);
    }
}

// ---------------------------------------------------------------------------
// Final pooling, stage 1: part[b][c][o] = sum_{s in chunk c} w[b][s]*H[b][s][o]
// grid (64 chunks, 8 batches); chunk = 32 seq rows; thread t covers cols 4t..4t+3
__global__ __launch_bounds__(256) void pool_partial(const float* __restrict__ w,
                                                    const bf16_t* __restrict__ H,
                                                    float* __restrict__ part) {
    const int b = blockIdx.y;
    const int c = blockIdx.x;
    const int t = threadIdx.x;
    const bf16_t* Hb = H + ((long)b*SEQ + (long)c*32)*DMODEL;
    const float*  wb = w + b*SEQ + c*32;
    f32x4 s = (f32x4)(0.f);
    #pragma unroll 4
    for (int i = 0; i < 32; ++i) {
        const float wi = wb[i];
        const bf16x4 hv = *(const bf16x4*)&Hb[(long)i*DMODEL + t*4];
        s[0] += wi * (float)hv[0];
        s[1] += wi * (float)hv[1];
        s[2] += wi * (float)hv[2];
        s[3] += wi * (float)hv[3];
    }
    *(f32x4*)&part[((long)b*64 + c)*DMODEL + t*4] = s;
}

// stage 2: out[b][o] = sum_c part[b][c][o]; 8192 threads
__global__ __launch_bounds__(256) void pool_reduce(const float* __restrict__ part,
                                                   float* __restrict__ out) {
    const int i = blockIdx.x*256 + threadIdx.x;   // 0..8191
    const int b = i >> 10, o = i & 1023;
    const float* p = part + (long)b*64*DMODEL + o;
    float s = 0.f;
    #pragma unroll
    for (int c = 0; c < 64; ++c) s += p[c*DMODEL];
    out[i] = s;
}

// ---------------------------------------------------------------------------
extern "C" void kernel_launch(void* const* d_in, const int* in_sizes, int n_in,
                              void* d_out, int out_size, void* d_ws, size_t ws_size,
                              hipStream_t stream) {
    (void)in_sizes; (void)n_in; (void)out_size; (void)ws_size;
    const float* inp = (const float*)d_in[0];
    const float* emw = (const float*)d_in[1];
    const float* emb = (const float*)d_in[2];
    const float* wqw = (const float*)d_in[3];
    const float* wqb = (const float*)d_in[4];
    const float* wkw = (const float*)d_in[5];
    const float* wkb = (const float*)d_in[6];
    const float* wvw = (const float*)d_in[7];
    const float* wvb = (const float*)d_in[8];
    const float* lng = (const float*)d_in[9];
    const float* lnb = (const float*)d_in[10];
    const float* skw = (const float*)d_in[11];
    const float* sq  = (const float*)d_in[12];
    const float* pos = (const float*)d_in[13];
    float* out = (float*)d_out;

    char* ws = (char*)d_ws;
    bf16_t* in_b   = (bf16_t*)(ws + 0);            // 16 MB (dead after embed; reused by pool partials)
    bf16_t* we_b   = (bf16_t*)(ws + 16777216);     // 1 MB
    bf16_t* wq_b   = (bf16_t*)(ws + 17825792);     // 2 MB
    bf16_t* wk_b   = (bf16_t*)(ws + 19922944);     // 2 MB
    bf16_t* wv_b   = (bf16_t*)(ws + 22020096);     // 2 MB
    bf16_t* sk_b   = (bf16_t*)(ws + 24117248);     // 2 MB
    float*  logits = (float*)(ws + 26214400);      // 64 KB
    float*  wsoft  = (float*)(ws + 26279936);      // 64 KB
    bf16_t* xb     = (bf16_t*)(ws + 26345472);     // 32 MB  x (bf16)
    bf16_t* Qb     = (bf16_t*)(ws + 59899904);     // 32 MB  Q, later h
    bf16_t* Kb     = (bf16_t*)(ws + 93454336);     // 32 MB
    bf16_t* VT     = (bf16_t*)(ws + 127008768);    // 32 MB  V^T per batch [1024][2048]
    bf16_t* Hb     = (bf16_t*)(ws + 160563200);    // 32 MB
    bf16_t* Pb     = (bf16_t*)(ws + 194117632);    // 64 MB  scores/probs
    float*  part   = (float*)(ws + 0);             // 2 MB pool partials (aliases dead in_b)

    // casts fp32 -> bf16
    cast_f32_bf16<<<8192, 256, 0, stream>>>(inp, in_b, 2097152);
    cast_f32_bf16<<<512,  256, 0, stream>>>(emw, we_b, 131072);
    cast_f32_bf16<<<1024, 256, 0, stream>>>(wqw, wq_b, 262144);
    cast_f32_bf16<<<1024, 256, 0, stream>>>(wkw, wk_b, 262144);
    cast_f32_bf16<<<1024, 256, 0, stream>>>(wvw, wv_b, 262144);
    cast_f32_bf16<<<1024, 256, 0, stream>>>(skw, sk_b, 262144);
    zero_f32_k<<<64, 256, 0, stream>>>(logits, NTOK);

    // x = inputs @ embed_w^T + bias + pos
    gemm_bt<0><<<dim3(8, 128, 1), 256, 0, stream>>>(in_b, we_b, xb, D_IN, DMODEL,
        0, 0, 0, emb, pos, nullptr, nullptr);
    // Q, K, V
    gemm_bt<1><<<dim3(8, 128, 1), 256, 0, stream>>>(xb, wq_b, Qb, DMODEL, DMODEL,
        0, 0, 0, wqb, nullptr, nullptr, nullptr);
    gemm_bt<1><<<dim3(8, 128, 1), 256, 0, stream>>>(xb, wk_b, Kb, DMODEL, DMODEL,
        0, 0, 0, wkb, nullptr, nullptr, nullptr);
    gemm_bt<2><<<dim3(8, 128, 1), 256, 0, stream>>>(xb, wv_b, VT, DMODEL, 0,
        0, 0, 0, wvb, nullptr, nullptr, nullptr);
    // S = Q K^T / 32 (per batch), bf16
    gemm_bt<3><<<dim3(16, 16, BATCH), 256, 0, stream>>>(Qb, Kb, Pb, DMODEL, SEQ,
        (long)SEQ*DMODEL, (long)SEQ*DMODEL, (long)SEQ*SEQ, nullptr, nullptr, nullptr, nullptr);
    softmax_rows_bf16<<<NTOK, 256, 0, stream>>>(Pb);
    // h = P V + x  (written over Q buffer)
    gemm_bt<4><<<dim3(8, 16, BATCH), 256, 0, stream>>>(Pb, VT, Qb, SEQ, DMODEL,
        (long)SEQ*SEQ, (long)DMODEL*SEQ, (long)SEQ*DMODEL, nullptr, nullptr, xb, nullptr);
    layernorm_k<<<NTOK, 256, 0, stream>>>(Qb, Hb, lng, lnb);
    // logits[m] = sum_n tanh(H skw^T) * soft_query[n]
    gemm_bt<5><<<dim3(8, 128, 1), 256, 0, stream>>>(Hb, sk_b, nullptr, DMODEL, 0,
        0, 0, 0, nullptr, sq, nullptr, logits);
    softmax_vec<<<BATCH, 256, 0, stream>>>(logits, wsoft);
    // pooled output: two-stage parallel reduction
    pool_partial<<<dim3(64, BATCH), 256, 0, stream>>>(wsoft, Hb, part);
    pool_reduce<<<32, 256, 0, stream>>>(part, out);
}

// Round 3
// 648.939 us; speedup vs baseline: 1.4627x; 1.0600x over previous
//
#include <hip/hip_runtime.h>
#include <hip/hip_bf16.h>
#include <math.h>

typedef __bf16 bf16_t;
typedef bf16_t bf16x8 __attribute__((ext_vector_type(8)));
typedef bf16_t bf16x4 __attribute__((ext_vector_type(4)));
typedef float  f32x4  __attribute__((ext_vector_type(4)));

#define D_IN   512
#define DMODEL 1024
#define SEQ    2048
#define BATCH  8
#define NTOK   (BATCH*SEQ)

typedef __attribute__((address_space(1))) unsigned int gu32;
typedef __attribute__((address_space(3))) unsigned int lu32;

__device__ __forceinline__ void async16(const void* g, void* l) {
    __builtin_amdgcn_global_load_lds((gu32*)g, (lu32*)l, 16, 0, 0);
}

// ---------------------------------------------------------------------------
// Unified bf16 GEMM: C[M,N] = A[M,K] * B[N,K]^T   (both row-major over K)
// 128x128 block tile, 4 waves, each wave 64x64 (4x4 grid of 16x16x32 MFMA).
// Launched as a 1D grid of gx*gy*gz blocks. Inside: XCD remap (round-robin ->
// contiguous per XCD) + 4x4 supertile decode so each XCD's live tile set
// (~4 MB) fits its private L2. For S/PV, each XCD handles exactly one batch.
// LDS: 16B k-chunks XOR-swizzled by (row>>1)&3 -> 2-way max bank aliasing (free).
// EPI: 0 = +bias[n] + pos_enc[m%SEQ][n]          (embed)
//      1 = +bias[n]                              (Q, K)
//      2 = +bias[n], write transposed -> VT[b][n][s]   (V)
//      3 = *1/32                                 (scores)
//      4 = +resid[m][n]                          (P*V + x -> h)
//      5 = logits[m] += sum_n tanh(C)*sq[n]      (soft_key, no C write)
// ---------------------------------------------------------------------------
template<int EPI>
__global__ __launch_bounds__(256)
void gemm_bt(const bf16_t* __restrict__ Ab, const bf16_t* __restrict__ Bb,
             bf16_t* __restrict__ Cb, int K, int ldc, int gx, int gy,
             long batchA, long batchB, long batchC,
             const float* __restrict__ bias, const float* __restrict__ aux_f,
             const bf16_t* __restrict__ resid, float* __restrict__ logits)
{
    __shared__ __align__(16) bf16_t As[128*32];
    __shared__ __align__(16) bf16_t Bs[128*32];

    const int tid  = threadIdx.x;
    const int lane = tid & 63;
    const int wave = tid >> 6;

    // --- block swizzle: XCD-contiguous + 4x4 supertiles ---
    const int flat = blockIdx.x;
    const int nb   = gridDim.x;                    // multiple of 8
    const int vid  = (flat & 7) * (nb >> 3) + (flat >> 3);
    const int pb   = gx * gy;                      // blocks per batch
    const int z    = vid / pb;
    const int w    = vid - z * pb;
    const int sy   = w / (gx * 4);
    const int r    = w - sy * (gx * 4);
    const int sx   = r >> 4;
    const int inner= r & 15;
    const int mtile = (sy * 4 + (inner & 3)) * 128;
    const int ntile = (sx * 4 + (inner >> 2)) * 128;

    const bf16_t* A  = Ab + (long)z * batchA;
    const bf16_t* Bp = Bb + (long)z * batchB;

    f32x4 acc[4][4];
    #pragma unroll
    for (int i = 0; i < 4; ++i)
        #pragma unroll
        for (int j = 0; j < 4; ++j)
            acc[i][j] = (f32x4)(0.f);

    const int lr = lane & 15;          // fragment row-in-tile
    const int lq = lane >> 4;          // quad 0..3 (logical k-chunk)
    const int wrow = (wave >> 1) * 64;
    const int wcol = (wave & 1) * 64;

    const int srow = lane >> 2;        // staging row within 16-row group
    // staging k-offset: lane's fixed LDS slot is phys chunk (lane&3) of row srow;
    // logical chunk there is (lane&3) ^ ((srow>>1)&3)  [swizzle]
    const int skq  = (((lane & 3) ^ ((lane >> 3) & 3)) * 8);
    // LDS read swizzle for fragment rows
    const int swA  = (lq ^ ((lr >> 1) & 3)) * 8;

    for (int k0 = 0; k0 < K; k0 += 32) {
        __syncthreads();               // previous iter's LDS reads done
        #pragma unroll
        for (int j = 0; j < 2; ++j) {
            const int grp = (wave << 1) + j;          // 0..7, 16 rows each
            const int row = (grp << 4) + srow;        // 0..127
            async16(A  + (long)(mtile + row) * K + (k0 + skq), &As[grp << 9]);
            async16(Bp + (long)(ntile + row) * K + (k0 + skq), &Bs[grp << 9]);
        }
        __syncthreads();               // drains vmcnt (global_load_lds) too

        bf16x8 af[4], bf[4];
        #pragma unroll
        for (int t = 0; t < 4; ++t)
            af[t] = *(const bf16x8*)&As[(wrow + t*16 + lr)*32 + swA];
        #pragma unroll
        for (int t = 0; t < 4; ++t)
            bf[t] = *(const bf16x8*)&Bs[(wcol + t*16 + lr)*32 + swA];
        #pragma unroll
        for (int tr = 0; tr < 4; ++tr)
            #pragma unroll
            for (int tc = 0; tc < 4; ++tc)
                acc[tr][tc] = __builtin_amdgcn_mfma_f32_16x16x32_bf16(
                                  af[tr], bf[tc], acc[tr][tc], 0, 0, 0);
    }

    // epilogue: C/D layout n = lane&15, m = (lane>>4)*4 + reg  [m89-verified]
    bf16_t* C = Cb + (long)z * batchC;
    const int mbase = mtile + wrow + lq*4;
    #pragma unroll
    for (int tr = 0; tr < 4; ++tr) {
        #pragma unroll
        for (int reg = 0; reg < 4; ++reg) {
            const int m = mbase + tr*16 + reg;
            if constexpr (EPI == 5) {
                float rs = 0.f;
                #pragma unroll
                for (int tc = 0; tc < 4; ++tc) {
                    const int n = ntile + wcol + tc*16 + lr;
                    rs += tanhf(acc[tr][tc][reg]) * aux_f[n];
                }
                rs += __shfl_xor(rs, 1);
                rs += __shfl_xor(rs, 2);
                rs += __shfl_xor(rs, 4);
                rs += __shfl_xor(rs, 8);
                if (lr == 0) atomicAdd(&logits[m], rs);
            } else {
                #pragma unroll
                for (int tc = 0; tc < 4; ++tc) {
                    const int n = ntile + wcol + tc*16 + lr;
                    float v = acc[tr][tc][reg];
                    if constexpr (EPI == 0) v += bias[n] + aux_f[(m & (SEQ-1))*DMODEL + n];
                    if constexpr (EPI == 1 || EPI == 2) v += bias[n];
                    if constexpr (EPI == 3) v *= 0.03125f;   // 1/sqrt(1024)
                    if constexpr (EPI == 4) v += (float)resid[(long)z*batchC + (long)m*ldc + n];
                    if constexpr (EPI == 2) {
                        // V transposed: VT[b][n][s], b = m/SEQ, s = m%SEQ
                        Cb[((long)(m >> 11)*DMODEL + n)*SEQ + (m & (SEQ-1))] = (bf16_t)v;
                    } else {
                        C[(long)m*ldc + n] = (bf16_t)v;
                    }
                }
            }
        }
    }
}

// ---------------------------------------------------------------------------
__global__ void cast_f32_bf16(const float* __restrict__ s, bf16_t* __restrict__ d, int n4) {
    int i = blockIdx.x*256 + threadIdx.x;
    if (i < n4) {
        const float4 f = ((const float4*)s)[i];
        bf16x4 o;
        o.x = (bf16_t)f.x; o.y = (bf16_t)f.y; o.z = (bf16_t)f.z; o.w = (bf16_t)f.w;
        ((bf16x4*)d)[i] = o;
    }
}

__global__ void zero_f32_k(float* __restrict__ p, int n) {
    int i = blockIdx.x*256 + threadIdx.x;
    if (i < n) p[i] = 0.f;
}

// row softmax over 2048 bf16, in place; one block per row
__global__ __launch_bounds__(256) void softmax_rows_bf16(bf16_t* __restrict__ P) {
    bf16_t* row = P + (long)blockIdx.x * SEQ;
    const int t = threadIdx.x, lane = t & 63, wave = t >> 6;
    __shared__ float sm[8];
    float v[8]; float mx = -3.0e38f;
    #pragma unroll
    for (int j = 0; j < 8; ++j) { v[j] = (float)row[t + 256*j]; mx = fmaxf(mx, v[j]); }
    #pragma unroll
    for (int o = 32; o; o >>= 1) mx = fmaxf(mx, __shfl_xor(mx, o));
    if (lane == 0) sm[wave] = mx;
    __syncthreads();
    mx = fmaxf(fmaxf(sm[0], sm[1]), fmaxf(sm[2], sm[3]));
    float s = 0.f;
    #pragma unroll
    for (int j = 0; j < 8; ++j) { v[j] = __expf(v[j] - mx); s += v[j]; }
    #pragma unroll
    for (int o = 32; o; o >>= 1) s += __shfl_xor(s, o);
    if (lane == 0) sm[4 + wave] = s;
    __syncthreads();
    s = (sm[4] + sm[5]) + (sm[6] + sm[7]);
    const float inv = 1.f / s;
    #pragma unroll
    for (int j = 0; j < 8; ++j) row[t + 256*j] = (bf16_t)(v[j] * inv);
}

// per-batch softmax over 2048 fp32 logits
__global__ __launch_bounds__(256) void softmax_vec(const float* __restrict__ L, float* __restrict__ W) {
    const float* l = L + (long)blockIdx.x * SEQ;
    float* w = W + (long)blockIdx.x * SEQ;
    const int t = threadIdx.x, lane = t & 63, wave = t >> 6;
    __shared__ float sm[8];
    float v[8]; float mx = -3.0e38f;
    #pragma unroll
    for (int j = 0; j < 8; ++j) { v[j] = l[t + 256*j]; mx = fmaxf(mx, v[j]); }
    #pragma unroll
    for (int o = 32; o; o >>= 1) mx = fmaxf(mx, __shfl_xor(mx, o));
    if (lane == 0) sm[wave] = mx;
    __syncthreads();
    mx = fmaxf(fmaxf(sm[0], sm[1]), fmaxf(sm[2], sm[3]));
    float s = 0.f;
    #pragma unroll
    for (int j = 0; j < 8; ++j) { v[j] = __expf(v[j] - mx); s += v[j]; }
    #pragma unroll
    for (int o = 32; o; o >>= 1) s += __shfl_xor(s, o);
    if (lane == 0) sm[4 + wave] = s;
    __syncthreads();
    s = (sm[4] + sm[5]) + (sm[6] + sm[7]);
    const float inv = 1.f / s;
    #pragma unroll
    for (int j = 0; j < 8; ++j) w[t + 256*j] = v[j] * inv;
}

// LayerNorm over 1024: one block per row, h bf16 -> H bf16
__global__ __launch_bounds__(256) void layernorm_k(const bf16_t* __restrict__ h, bf16_t* __restrict__ H,
                                                   const float* __restrict__ gam, const float* __restrict__ bet) {
    const long row = blockIdx.x;
    const bf16_t* hr = h + row*DMODEL;
    bf16_t* Hr = H + row*DMODEL;
    const int t = threadIdx.x, lane = t & 63, wave = t >> 6;
    __shared__ float sm[8];
    float v[4]; float s = 0.f, q = 0.f;
    #pragma unroll
    for (int j = 0; j < 4; ++j) { v[j] = (float)hr[t + 256*j]; s += v[j]; q += v[j]*v[j]; }
    #pragma unroll
    for (int o = 32; o; o >>= 1) { s += __shfl_xor(s, o); q += __shfl_xor(q, o); }
    if (lane == 0) { sm[wave] = s; sm[4 + wave] = q; }
    __syncthreads();
    s = (sm[0] + sm[1]) + (sm[2] + sm[3]);
    q = (sm[4] + sm[5]) + (sm[6] + sm[7]);
    const float mu  = s * (1.f/DMODEL);
    const float var = q * (1.f/DMODEL) - mu*mu;
    const float r   = rsqrtf(var + 1e-5f);
    #pragma unroll
    for (int j = 0; j < 4; ++j) {
        const int n = t + 256*j;
        Hr[n] = (bf16_t)((v[j] - mu)*r*gam[n] + bet[n]);
    }
}

// ---------------------------------------------------------------------------
// Final pooling, stage 1: part[b][c][o] = sum_{s in chunk c} w[b][s]*H[b][s][o]
__global__ __launch_bounds__(256) void pool_partial(const float* __restrict__ w,
                                                    const bf16_t* __restrict__ H,
                                                    float* __restrict__ part) {
    const int b = blockIdx.y;
    const int c = blockIdx.x;
    const int t = threadIdx.x;
    const bf16_t* Hb = H + ((long)b*SEQ + (long)c*32)*DMODEL;
    const float*  wb = w + b*SEQ + c*32;
    f32x4 s = (f32x4)(0.f);
    #pragma unroll 4
    for (int i = 0; i < 32; ++i) {
        const float wi = wb[i];
        const bf16x4 hv = *(const bf16x4*)&Hb[(long)i*DMODEL + t*4];
        s[0] += wi * (float)hv[0];
        s[1] += wi * (float)hv[1];
        s[2] += wi * (float)hv[2];
        s[3] += wi * (float)hv[3];
    }
    *(f32x4*)&part[((long)b*64 + c)*DMODEL + t*4] = s;
}

// stage 2: out[b][o] = sum_c part[b][c][o]; 8192 threads
__global__ __launch_bounds__(256) void pool_reduce(const float* __restrict__ part,
                                                   float* __restrict__ out) {
    const int i = blockIdx.x*256 + threadIdx.x;   // 0..8191
    const int b = i >> 10, o = i & 1023;
    const float* p = part + (long)b*64*DMODEL + o;
    float s = 0.f;
    #pragma unroll
    for (int c = 0; c < 64; ++c) s += p[c*DMODEL];
    out[i] = s;
}

// ---------------------------------------------------------------------------
extern "C" void kernel_launch(void* const* d_in, const int* in_sizes, int n_in,
                              void* d_out, int out_size, void* d_ws, size_t ws_size,
                              hipStream_t stream) {
    (void)in_sizes; (void)n_in; (void)out_size; (void)ws_size;
    const float* inp = (const float*)d_in[0];
    const float* emw = (const float*)d_in[1];
    const float* emb = (const float*)d_in[2];
    const float* wqw = (const float*)d_in[3];
    const float* wqb = (const float*)d_in[4];
    const float* wkw = (const float*)d_in[5];
    const float* wkb = (const float*)d_in[6];
    const float* wvw = (const float*)d_in[7];
    const float* wvb = (const float*)d_in[8];
    const float* lng = (const float*)d_in[9];
    const float* lnb = (const float*)d_in[10];
    const float* skw = (const float*)d_in[11];
    const float* sq  = (const float*)d_in[12];
    const float* pos = (const float*)d_in[13];
    float* out = (float*)d_out;

    char* ws = (char*)d_ws;
    bf16_t* in_b   = (bf16_t*)(ws + 0);            // 16 MB (dead after embed; reused by pool partials)
    bf16_t* we_b   = (bf16_t*)(ws + 16777216);     // 1 MB
    bf16_t* wq_b   = (bf16_t*)(ws + 17825792);     // 2 MB
    bf16_t* wk_b   = (bf16_t*)(ws + 19922944);     // 2 MB
    bf16_t* wv_b   = (bf16_t*)(ws + 22020096);     // 2 MB
    bf16_t* sk_b   = (bf16_t*)(ws + 24117248);     // 2 MB
    float*  logits = (float*)(ws + 26214400);      // 64 KB
    float*  wsoft  = (float*)(ws + 26279936);      // 64 KB
    bf16_t* xb     = (bf16_t*)(ws + 26345472);     // 32 MB  x (bf16)
    bf16_t* Qb     = (bf16_t*)(ws + 59899904);     // 32 MB  Q, later h
    bf16_t* Kb     = (bf16_t*)(ws + 93454336);     // 32 MB
    bf16_t* VT     = (bf16_t*)(ws + 127008768);    // 32 MB  V^T per batch [1024][2048]
    bf16_t* Hb     = (bf16_t*)(ws + 160563200);    // 32 MB
    bf16_t* Pb     = (bf16_t*)(ws + 194117632);    // 64 MB  scores/probs
    float*  part   = (float*)(ws + 0);             // 2 MB pool partials (aliases dead in_b)

    // casts fp32 -> bf16
    cast_f32_bf16<<<8192, 256, 0, stream>>>(inp, in_b, 2097152);
    cast_f32_bf16<<<512,  256, 0, stream>>>(emw, we_b, 131072);
    cast_f32_bf16<<<1024, 256, 0, stream>>>(wqw, wq_b, 262144);
    cast_f32_bf16<<<1024, 256, 0, stream>>>(wkw, wk_b, 262144);
    cast_f32_bf16<<<1024, 256, 0, stream>>>(wvw, wv_b, 262144);
    cast_f32_bf16<<<1024, 256, 0, stream>>>(skw, sk_b, 262144);
    zero_f32_k<<<64, 256, 0, stream>>>(logits, NTOK);

    // x = inputs @ embed_w^T + bias + pos       (gx=8 n-tiles, gy=128 m-tiles)
    gemm_bt<0><<<1024, 256, 0, stream>>>(in_b, we_b, xb, D_IN, DMODEL, 8, 128,
        0, 0, 0, emb, pos, nullptr, nullptr);
    // Q, K, V
    gemm_bt<1><<<1024, 256, 0, stream>>>(xb, wq_b, Qb, DMODEL, DMODEL, 8, 128,
        0, 0, 0, wqb, nullptr, nullptr, nullptr);
    gemm_bt<1><<<1024, 256, 0, stream>>>(xb, wk_b, Kb, DMODEL, DMODEL, 8, 128,
        0, 0, 0, wkb, nullptr, nullptr, nullptr);
    gemm_bt<2><<<1024, 256, 0, stream>>>(xb, wv_b, VT, DMODEL, 0, 8, 128,
        0, 0, 0, wvb, nullptr, nullptr, nullptr);
    // S = Q K^T / 32 (per batch), bf16          (one full batch per XCD)
    gemm_bt<3><<<2048, 256, 0, stream>>>(Qb, Kb, Pb, DMODEL, SEQ, 16, 16,
        (long)SEQ*DMODEL, (long)SEQ*DMODEL, (long)SEQ*SEQ, nullptr, nullptr, nullptr, nullptr);
    softmax_rows_bf16<<<NTOK, 256, 0, stream>>>(Pb);
    // h = P V + x  (written over Q buffer)      (one full batch per XCD)
    gemm_bt<4><<<1024, 256, 0, stream>>>(Pb, VT, Qb, SEQ, DMODEL, 8, 16,
        (long)SEQ*SEQ, (long)DMODEL*SEQ, (long)SEQ*DMODEL, nullptr, nullptr, xb, nullptr);
    layernorm_k<<<NTOK, 256, 0, stream>>>(Qb, Hb, lng, lnb);
    // logits[m] = sum_n tanh(H skw^T) * soft_query[n]
    gemm_bt<5><<<1024, 256, 0, stream>>>(Hb, sk_b, nullptr, DMODEL, 0, 8, 128,
        0, 0, 0, nullptr, sq, nullptr, logits);
    softmax_vec<<<BATCH, 256, 0, stream>>>(logits, wsoft);
    // pooled output: two-stage parallel reduction
    pool_partial<<<dim3(64, BATCH), 256, 0, stream>>>(wsoft, Hb, part);
    pool_reduce<<<32, 256, 0, stream>>>(part, out);
}

// Round 5
// 620.402 us; speedup vs baseline: 1.5300x; 1.0460x over previous
//
#include <hip/hip_runtime.h>
#include <hip/hip_bf16.h>
#include <math.h>

typedef __bf16 bf16_t;
typedef bf16_t bf16x8 __attribute__((ext_vector_type(8)));
typedef bf16_t bf16x4 __attribute__((ext_vector_type(4)));
typedef float  f32x4  __attribute__((ext_vector_type(4)));

#define D_IN   512
#define DMODEL 1024
#define SEQ    2048
#define BATCH  8
#define NTOK   (BATCH*SEQ)

typedef __attribute__((address_space(1))) unsigned int gu32;
typedef __attribute__((address_space(3))) unsigned int lu32;

__device__ __forceinline__ void async16(const void* g, void* l) {
    __builtin_amdgcn_global_load_lds((gu32*)g, (lu32*)l, 16, 0, 0);
}

// ---------------------------------------------------------------------------
// Unified bf16 GEMM: C[M,N] = A[M,K] * B[N,K]^T   (both row-major over K)
// 128x128 block tile, 4 waves, each 64x64 (4x4 of 16x16x32 MFMA).
// 1D grid; XCD-contiguous remap + 4x4 supertiles for L2 locality.
// K-loop LDS XOR-swizzled (zero bank conflicts, verified R3).
// Epilogue: acc -> LDS tile -> coalesced bf16x8 stores.
//   EPI=4 stages in *fp32* (64 KB LDS) so h = bf16(Z_f32 + x) rounds ONCE —
//   double bf16 rounding in R4 cost 0.031 absmax and failed the 0.07 gate.
// EPI: 0 = +bias[n] + pos_enc[m%SEQ][n]                     (embed)
//      3 = *1/32                                            (scores)
//      4 = +resid[m][n] (fp32 staging)                      (P*V + x -> h)
//      5 = logits[m] += sum_n tanh(C)*sq[n], no C write     (soft_key)
//      6 = fused QKV: N=3072; seg=ntile>>10 -> Q | K | V^T  (+ per-seg bias)
// ---------------------------------------------------------------------------
template<int EPI>
__global__ __launch_bounds__(256)
void gemm_bt(const bf16_t* __restrict__ Ab, const bf16_t* __restrict__ Bb,
             bf16_t* __restrict__ Cb, int K, int ldc, int gx, int gy,
             long batchA, long batchB, long batchC,
             const float* __restrict__ bias, const float* __restrict__ aux_f,
             const bf16_t* __restrict__ resid, float* __restrict__ logits,
             const float* __restrict__ bias3)
{
    constexpr int SMEM_ELEMS = (EPI == 4) ? 32768 : 16384;   // 64 KB : 32 KB
    __shared__ __align__(16) bf16_t smem[SMEM_ELEMS];  // K-loop: As|Bs ; epilogue: C tile
    bf16_t* As = smem;
    bf16_t* Bs = smem + 4096;

    const int tid  = threadIdx.x;
    const int lane = tid & 63;
    const int wave = tid >> 6;

    // --- block swizzle: XCD-contiguous + 4x4 supertiles ---
    const int flat = blockIdx.x;
    const int nb   = gridDim.x;                    // multiple of 8
    const int vid  = (flat & 7) * (nb >> 3) + (flat >> 3);
    const int pb   = gx * gy;                      // blocks per batch
    const int z    = vid / pb;
    const int w    = vid - z * pb;
    const int sy   = w / (gx * 4);
    const int r    = w - sy * (gx * 4);
    const int sx   = r >> 4;
    const int inner= r & 15;
    const int mtile = (sy * 4 + (inner & 3)) * 128;
    const int ntile = (sx * 4 + (inner >> 2)) * 128;

    const bf16_t* A  = Ab + (long)z * batchA;
    const bf16_t* Bp = Bb + (long)z * batchB;

    f32x4 acc[4][4];
    #pragma unroll
    for (int i = 0; i < 4; ++i)
        #pragma unroll
        for (int j = 0; j < 4; ++j)
            acc[i][j] = (f32x4)(0.f);

    const int lr = lane & 15;          // fragment row-in-tile
    const int lq = lane >> 4;          // quad 0..3 (logical k-chunk)
    const int wrow = (wave >> 1) * 64;
    const int wcol = (wave & 1) * 64;

    const int srow = lane >> 2;        // staging row within 16-row group
    const int skq  = (((lane & 3) ^ ((lane >> 3) & 3)) * 8);   // swizzled k-offset
    const int swA  = (lq ^ ((lr >> 1) & 3)) * 8;               // swizzled read offset

    for (int k0 = 0; k0 < K; k0 += 32) {
        __syncthreads();               // previous iter's LDS reads done
        #pragma unroll
        for (int j = 0; j < 2; ++j) {
            const int grp = (wave << 1) + j;          // 0..7, 16 rows each
            const int row = (grp << 4) + srow;        // 0..127
            async16(A  + (long)(mtile + row) * K + (k0 + skq), &As[grp << 9]);
            async16(Bp + (long)(ntile + row) * K + (k0 + skq), &Bs[grp << 9]);
        }
        __syncthreads();               // drains vmcnt (global_load_lds) too

        bf16x8 af[4], bf[4];
        #pragma unroll
        for (int t = 0; t < 4; ++t)
            af[t] = *(const bf16x8*)&As[(wrow + t*16 + lr)*32 + swA];
        #pragma unroll
        for (int t = 0; t < 4; ++t)
            bf[t] = *(const bf16x8*)&Bs[(wcol + t*16 + lr)*32 + swA];
        #pragma unroll
        for (int tr = 0; tr < 4; ++tr)
            #pragma unroll
            for (int tc = 0; tc < 4; ++tc)
                acc[tr][tc] = __builtin_amdgcn_mfma_f32_16x16x32_bf16(
                                  af[tr], bf[tc], acc[tr][tc], 0, 0, 0);
    }

    // C/D layout: n = lane&15, m = (lane>>4)*4 + reg  [m89-verified]
    if constexpr (EPI == 5) {
        const int mbase = mtile + wrow + lq*4;
        #pragma unroll
        for (int tr = 0; tr < 4; ++tr) {
            #pragma unroll
            for (int reg = 0; reg < 4; ++reg) {
                const int m = mbase + tr*16 + reg;
                float rs = 0.f;
                #pragma unroll
                for (int tc = 0; tc < 4; ++tc) {
                    const int n = ntile + wcol + tc*16 + lr;
                    rs += tanhf(acc[tr][tc][reg]) * aux_f[n];
                }
                rs += __shfl_xor(rs, 1);
                rs += __shfl_xor(rs, 2);
                rs += __shfl_xor(rs, 4);
                rs += __shfl_xor(rs, 8);
                if (lr == 0) atomicAdd(&logits[m], rs);
            }
        }
        return;
    }

    // ---- staged epilogue ----
    __syncthreads();                   // all waves done reading As/Bs

    if constexpr (EPI == 4) {
        // fp32 LDS staging (64 KB): single bf16 rounding of h = Z + x.
        // Swizzle: 16B (4-float) chunks XOR rl&31 -> <=2-way banking (free).
        float* fsm = (float*)smem;     // [128][128] fp32
        #pragma unroll
        for (int tr = 0; tr < 4; ++tr) {
            #pragma unroll
            for (int reg = 0; reg < 4; ++reg) {
                const int rl = wrow + tr*16 + lq*4 + reg;
                #pragma unroll
                for (int tc = 0; tc < 4; ++tc) {
                    const int cl = wcol + tc*16 + lr;
                    fsm[rl*128 + ((((cl >> 2) ^ (rl & 31)) << 2) | (cl & 3))] = acc[tr][tc][reg];
                }
            }
        }
        __syncthreads();
        bf16_t* C = Cb + (long)z * batchC;
        const int chunk = tid & 15;    // 8 consecutive cols
        const int grp   = tid >> 4;
        #pragma unroll
        for (int rep = 0; rep < 8; ++rep) {
            const int R  = grp + rep*16;
            const int c0 = chunk*8;
            const int p0 = (((c0 >> 2)       ^ (R & 31)) << 2);
            const int p1 = ((((c0 + 4) >> 2) ^ (R & 31)) << 2);
            const f32x4 f0 = *(const f32x4*)&fsm[R*128 + p0];
            const f32x4 f1 = *(const f32x4*)&fsm[R*128 + p1];
            const long off = (long)(mtile + R)*ldc + ntile + c0;
            const bf16x8 r8 = *(const bf16x8*)&resid[(long)z*batchC + off];
            bf16x8 val;
            #pragma unroll
            for (int i = 0; i < 4; ++i) {
                val[i]     = (bf16_t)(f0[i] + (float)r8[i]);
                val[i + 4] = (bf16_t)(f1[i] + (float)r8[i + 4]);
            }
            *(bf16x8*)&C[off] = val;
        }
        return;
    }

    const int seg = (EPI == 6) ? (ntile >> 10) : 0;
    const float* bp = bias;
    if constexpr (EPI == 6) bp = (seg == 0) ? bias : (seg == 1) ? aux_f : bias3;

    // stage 1: registers -> LDS bf16 (col-chunk XOR row&7 swizzle -> ~2-way, free)
    #pragma unroll
    for (int tr = 0; tr < 4; ++tr) {
        #pragma unroll
        for (int reg = 0; reg < 4; ++reg) {
            const int rl = wrow + tr*16 + lq*4 + reg;        // 0..127
            #pragma unroll
            for (int tc = 0; tc < 4; ++tc) {
                const int cl = wcol + tc*16 + lr;            // 0..127
                float v = acc[tr][tc][reg];
                if constexpr (EPI == 0)
                    v += bias[ntile + cl] + aux_f[((mtile + rl) & (SEQ-1))*DMODEL + ntile + cl];
                if constexpr (EPI == 3) v *= 0.03125f;       // 1/sqrt(1024)
                if constexpr (EPI == 6) v += bp[(ntile + cl) & 1023];
                smem[rl*128 + ((((cl >> 3) ^ (rl & 7)) << 3) | (cl & 7))] = (bf16_t)v;
            }
        }
    }
    __syncthreads();

    // stage 2: LDS -> global, coalesced
    if constexpr (EPI == 6) {
        if (seg == 2) {
            // V transposed: VT[b][n][s]; contiguous dim = s = m
            bf16_t* VTb = Cb + 33554432;                     // Qb + 32M elems (64 MB)
            const int col  = tid & 127;                      // n_local within tile
            const int half = tid >> 7;
            const int b    = mtile >> 11, s0 = mtile & (SEQ-1);
            const long nbase = (long)b*DMODEL + (ntile & 1023) + col;
            #pragma unroll
            for (int rep = 0; rep < 8; ++rep) {
                const int R0 = half*64 + rep*8;
                bf16x8 o;
                #pragma unroll
                for (int i = 0; i < 8; ++i) {
                    const int rl = R0 + i;
                    o[i] = smem[rl*128 + ((((col >> 3) ^ (rl & 7)) << 3) | (col & 7))];
                }
                *(bf16x8*)&VTb[nbase*SEQ + s0 + R0] = o;
            }
            return;
        }
        const int chunk = tid & 15;
        const int grp   = tid >> 4;
        const long base = (long)seg * 16777216 + (ntile & 1023) + chunk*8;
        #pragma unroll
        for (int rep = 0; rep < 8; ++rep) {
            const int R = grp + rep*16;
            const int phys = chunk ^ (R & 7);
            bf16x8 val = *(const bf16x8*)&smem[R*128 + phys*8];
            *(bf16x8*)&Cb[base + (long)(mtile + R)*1024] = val;
        }
        return;
    }

    bf16_t* C = Cb + (long)z * batchC;
    const int chunk = tid & 15;
    const int grp   = tid >> 4;
    #pragma unroll
    for (int rep = 0; rep < 8; ++rep) {
        const int R = grp + rep*16;
        const int phys = chunk ^ (R & 7);
        bf16x8 val = *(const bf16x8*)&smem[R*128 + phys*8];
        const long off = (long)(mtile + R)*ldc + ntile + chunk*8;
        *(bf16x8*)&C[off] = val;
    }
}

// ---------------------------------------------------------------------------
__global__ void cast_f32_bf16(const float* __restrict__ s, bf16_t* __restrict__ d, int n4) {
    int i = blockIdx.x*256 + threadIdx.x;
    if (i < n4) {
        const float4 f = ((const float4*)s)[i];
        bf16x4 o;
        o.x = (bf16_t)f.x; o.y = (bf16_t)f.y; o.z = (bf16_t)f.z; o.w = (bf16_t)f.w;
        ((bf16x4*)d)[i] = o;
    }
}

__global__ void zero_f32_k(float* __restrict__ p, int n) {
    int i = blockIdx.x*256 + threadIdx.x;
    if (i < n) p[i] = 0.f;
}

// row softmax over 2048 bf16, in place; one block per row
__global__ __launch_bounds__(256) void softmax_rows_bf16(bf16_t* __restrict__ P) {
    bf16_t* row = P + (long)blockIdx.x * SEQ;
    const int t = threadIdx.x, lane = t & 63, wave = t >> 6;
    __shared__ float sm[8];
    float v[8]; float mx = -3.0e38f;
    #pragma unroll
    for (int j = 0; j < 8; ++j) { v[j] = (float)row[t + 256*j]; mx = fmaxf(mx, v[j]); }
    #pragma unroll
    for (int o = 32; o; o >>= 1) mx = fmaxf(mx, __shfl_xor(mx, o));
    if (lane == 0) sm[wave] = mx;
    __syncthreads();
    mx = fmaxf(fmaxf(sm[0], sm[1]), fmaxf(sm[2], sm[3]));
    float s = 0.f;
    #pragma unroll
    for (int j = 0; j < 8; ++j) { v[j] = __expf(v[j] - mx); s += v[j]; }
    #pragma unroll
    for (int o = 32; o; o >>= 1) s += __shfl_xor(s, o);
    if (lane == 0) sm[4 + wave] = s;
    __syncthreads();
    s = (sm[4] + sm[5]) + (sm[6] + sm[7]);
    const float inv = 1.f / s;
    #pragma unroll
    for (int j = 0; j < 8; ++j) row[t + 256*j] = (bf16_t)(v[j] * inv);
}

// per-batch softmax over 2048 fp32 logits
__global__ __launch_bounds__(256) void softmax_vec(const float* __restrict__ L, float* __restrict__ W) {
    const float* l = L + (long)blockIdx.x * SEQ;
    float* w = W + (long)blockIdx.x * SEQ;
    const int t = threadIdx.x, lane = t & 63, wave = t >> 6;
    __shared__ float sm[8];
    float v[8]; float mx = -3.0e38f;
    #pragma unroll
    for (int j = 0; j < 8; ++j) { v[j] = l[t + 256*j]; mx = fmaxf(mx, v[j]); }
    #pragma unroll
    for (int o = 32; o; o >>= 1) mx = fmaxf(mx, __shfl_xor(mx, o));
    if (lane == 0) sm[wave] = mx;
    __syncthreads();
    mx = fmaxf(fmaxf(sm[0], sm[1]), fmaxf(sm[2], sm[3]));
    float s = 0.f;
    #pragma unroll
    for (int j = 0; j < 8; ++j) { v[j] = __expf(v[j] - mx); s += v[j]; }
    #pragma unroll
    for (int o = 32; o; o >>= 1) s += __shfl_xor(s, o);
    if (lane == 0) sm[4 + wave] = s;
    __syncthreads();
    s = (sm[4] + sm[5]) + (sm[6] + sm[7]);
    const float inv = 1.f / s;
    #pragma unroll
    for (int j = 0; j < 8; ++j) w[t + 256*j] = v[j] * inv;
}

// LayerNorm over 1024: one block per row, h bf16 -> H bf16
__global__ __launch_bounds__(256) void layernorm_k(const bf16_t* __restrict__ h, bf16_t* __restrict__ H,
                                                   const float* __restrict__ gam, const float* __restrict__ bet) {
    const long row = blockIdx.x;
    const bf16_t* hr = h + row*DMODEL;
    bf16_t* Hr = H + row*DMODEL;
    const int t = threadIdx.x, lane = t & 63, wave = t >> 6;
    __shared__ float sm[8];
    float v[4]; float s = 0.f, q = 0.f;
    #pragma unroll
    for (int j = 0; j < 4; ++j) { v[j] = (float)hr[t + 256*j]; s += v[j]; q += v[j]*v[j]; }
    #pragma unroll
    for (int o = 32; o; o >>= 1) { s += __shfl_xor(s, o); q += __shfl_xor(q, o); }
    if (lane == 0) { sm[wave] = s; sm[4 + wave] = q; }
    __syncthreads();
    s = (sm[0] + sm[1]) + (sm[2] + sm[3]);
    q = (sm[4] + sm[5]) + (sm[6] + sm[7]);
    const float mu  = s * (1.f/DMODEL);
    const float var = q * (1.f/DMODEL) - mu*mu;
    const float r   = rsqrtf(var + 1e-5f);
    #pragma unroll
    for (int j = 0; j < 4; ++j) {
        const int n = t + 256*j;
        Hr[n] = (bf16_t)((v[j] - mu)*r*gam[n] + bet[n]);
    }
}

// ---------------------------------------------------------------------------
// Final pooling, stage 1: part[b][c][o] = sum_{s in chunk c} w[b][s]*H[b][s][o]
__global__ __launch_bounds__(256) void pool_partial(const float* __restrict__ w,
                                                    const bf16_t* __restrict__ H,
                                                    float* __restrict__ part) {
    const int b = blockIdx.y;
    const int c = blockIdx.x;
    const int t = threadIdx.x;
    const bf16_t* Hb = H + ((long)b*SEQ + (long)c*32)*DMODEL;
    const float*  wb = w + b*SEQ + c*32;
    f32x4 s = (f32x4)(0.f);
    #pragma unroll 4
    for (int i = 0; i < 32; ++i) {
        const float wi = wb[i];
        const bf16x4 hv = *(const bf16x4*)&Hb[(long)i*DMODEL + t*4];
        s[0] += wi * (float)hv[0];
        s[1] += wi * (float)hv[1];
        s[2] += wi * (float)hv[2];
        s[3] += wi * (float)hv[3];
    }
    *(f32x4*)&part[((long)b*64 + c)*DMODEL + t*4] = s;
}

// stage 2: out[b][o] = sum_c part[b][c][o]; 8192 threads
__global__ __launch_bounds__(256) void pool_reduce(const float* __restrict__ part,
                                                   float* __restrict__ out) {
    const int i = blockIdx.x*256 + threadIdx.x;   // 0..8191
    const int b = i >> 10, o = i & 1023;
    const float* p = part + (long)b*64*DMODEL + o;
    float s = 0.f;
    #pragma unroll
    for (int c = 0; c < 64; ++c) s += p[c*DMODEL];
    out[i] = s;
}

// ---------------------------------------------------------------------------
extern "C" void kernel_launch(void* const* d_in, const int* in_sizes, int n_in,
                              void* d_out, int out_size, void* d_ws, size_t ws_size,
                              hipStream_t stream) {
    (void)in_sizes; (void)n_in; (void)out_size; (void)ws_size;
    const float* inp = (const float*)d_in[0];
    const float* emw = (const float*)d_in[1];
    const float* emb = (const float*)d_in[2];
    const float* wqw = (const float*)d_in[3];
    const float* wqb = (const float*)d_in[4];
    const float* wkw = (const float*)d_in[5];
    const float* wkb = (const float*)d_in[6];
    const float* wvw = (const float*)d_in[7];
    const float* wvb = (const float*)d_in[8];
    const float* lng = (const float*)d_in[9];
    const float* lnb = (const float*)d_in[10];
    const float* skw = (const float*)d_in[11];
    const float* sq  = (const float*)d_in[12];
    const float* pos = (const float*)d_in[13];
    float* out = (float*)d_out;

    char* ws = (char*)d_ws;
    bf16_t* in_b   = (bf16_t*)(ws + 0);            // 16 MB (dead after embed; reused by pool partials)
    bf16_t* we_b   = (bf16_t*)(ws + 16777216);     // 1 MB
    bf16_t* wq_b   = (bf16_t*)(ws + 17825792);     // 2 MB  } contiguous [3072][1024]
    bf16_t* wk_b   = (bf16_t*)(ws + 19922944);     // 2 MB  }
    bf16_t* wv_b   = (bf16_t*)(ws + 22020096);     // 2 MB  }
    bf16_t* sk_b   = (bf16_t*)(ws + 24117248);     // 2 MB
    float*  logits = (float*)(ws + 26214400);      // 64 KB
    float*  wsoft  = (float*)(ws + 26279936);      // 64 KB
    bf16_t* xb     = (bf16_t*)(ws + 26345472);     // 32 MB  x (bf16)
    bf16_t* Qb     = (bf16_t*)(ws + 59899904);     // 32 MB  Q, later h   } Q|K|VT contiguous
    bf16_t* Kb     = (bf16_t*)(ws + 93454336);     // 32 MB               }
    bf16_t* VT     = (bf16_t*)(ws + 127008768);    // 32 MB  V^T [b][1024][2048]
    bf16_t* Hb     = (bf16_t*)(ws + 160563200);    // 32 MB
    bf16_t* Pb     = (bf16_t*)(ws + 194117632);    // 64 MB  scores/probs
    float*  part   = (float*)(ws + 0);             // 2 MB pool partials (aliases dead in_b)

    // casts fp32 -> bf16
    cast_f32_bf16<<<8192, 256, 0, stream>>>(inp, in_b, 2097152);
    cast_f32_bf16<<<512,  256, 0, stream>>>(emw, we_b, 131072);
    cast_f32_bf16<<<1024, 256, 0, stream>>>(wqw, wq_b, 262144);
    cast_f32_bf16<<<1024, 256, 0, stream>>>(wkw, wk_b, 262144);
    cast_f32_bf16<<<1024, 256, 0, stream>>>(wvw, wv_b, 262144);
    cast_f32_bf16<<<1024, 256, 0, stream>>>(skw, sk_b, 262144);
    zero_f32_k<<<64, 256, 0, stream>>>(logits, NTOK);

    // x = inputs @ embed_w^T + bias + pos       (gx=8 n-tiles, gy=128 m-tiles)
    gemm_bt<0><<<1024, 256, 0, stream>>>(in_b, we_b, xb, D_IN, DMODEL, 8, 128,
        0, 0, 0, emb, pos, nullptr, nullptr, nullptr);
    // fused QKV: N=3072 over contiguous weights; writes Q | K | VT
    gemm_bt<6><<<3072, 256, 0, stream>>>(xb, wq_b, Qb, DMODEL, DMODEL, 24, 128,
        0, 0, 0, wqb, wkb, nullptr, nullptr, wvb);
    // S = Q K^T / 32 (per batch), bf16          (one full batch per XCD)
    gemm_bt<3><<<2048, 256, 0, stream>>>(Qb, Kb, Pb, DMODEL, SEQ, 16, 16,
        (long)SEQ*DMODEL, (long)SEQ*DMODEL, (long)SEQ*SEQ, nullptr, nullptr, nullptr, nullptr, nullptr);
    softmax_rows_bf16<<<NTOK, 256, 0, stream>>>(Pb);
    // h = P V + x  (written over Q buffer)      (one full batch per XCD)
    gemm_bt<4><<<1024, 256, 0, stream>>>(Pb, VT, Qb, SEQ, DMODEL, 8, 16,
        (long)SEQ*SEQ, (long)DMODEL*SEQ, (long)SEQ*DMODEL, nullptr, nullptr, xb, nullptr, nullptr);
    layernorm_k<<<NTOK, 256, 0, stream>>>(Qb, Hb, lng, lnb);
    // logits[m] = sum_n tanh(H skw^T) * soft_query[n]
    gemm_bt<5><<<1024, 256, 0, stream>>>(Hb, sk_b, nullptr, DMODEL, 0, 8, 128,
        0, 0, 0, nullptr, sq, nullptr, logits, nullptr);
    softmax_vec<<<BATCH, 256, 0, stream>>>(logits, wsoft);
    // pooled output: two-stage parallel reduction
    pool_partial<<<dim3(64, BATCH), 256, 0, stream>>>(wsoft, Hb, part);
    pool_reduce<<<32, 256, 0, stream>>>(part, out);
}

// Round 6
// 552.422 us; speedup vs baseline: 1.7182x; 1.1231x over previous
//
#include <hip/hip_runtime.h>
#include <hip/hip_bf16.h>
#include <math.h>

typedef __bf16 bf16_t;
typedef bf16_t bf16x8 __attribute__((ext_vector_type(8)));
typedef bf16_t bf16x4 __attribute__((ext_vector_type(4)));
typedef float  f32x4  __attribute__((ext_vector_type(4)));

#define D_IN   512
#define DMODEL 1024
#define SEQ    2048
#define BATCH  8
#define NTOK   (BATCH*SEQ)

typedef __attribute__((address_space(1))) unsigned int gu32;
typedef __attribute__((address_space(3))) unsigned int lu32;

__device__ __forceinline__ void async16(const void* g, void* l) {
    __builtin_amdgcn_global_load_lds((gu32*)g, (lu32*)l, 16, 0, 0);
}

// ---------------------------------------------------------------------------
// Unified bf16 GEMM: C[M,N] = A[M,K] * B[N,K]^T   (both row-major over K)
// 128x128 block tile, 4 waves, each 64x64 (4x4 of 16x16x32 MFMA).
// BK=64 K-loop (R6): 32 MFMA per barrier-pair (was 16) — halves the
// vmcnt(0)+s_barrier drains that cap the m97 2-barrier structure.
// LDS 32 KB K-loop; swizzle: 16B chunk phys = logical ^ (row&7) -> both the
// async16 staging and ds_read_b128 fragment reads are conflict-free.
// 1D grid; XCD-contiguous remap + 4x4 supertiles for L2 locality (R3).
// Epilogue: acc -> LDS tile -> coalesced bf16x8 stores (R4); EPI=4 stages in
// fp32 (64 KB) so h = bf16(Z_f32 + x) rounds ONCE (R5 numerics fix).
// EPI: 0 = +bias[n] + pos_enc[m%SEQ][n]                     (embed)
//      3 = *1/32                                            (scores)
//      4 = +resid[m][n] (fp32 staging)                      (P*V + x -> h)
//      5 = logits[m] += sum_n tanh(C)*sq[n], no C write     (soft_key)
//      6 = fused QKV: N=3072; seg=ntile>>10 -> Q | K | V^T  (+ per-seg bias)
// ---------------------------------------------------------------------------
template<int EPI>
__global__ __launch_bounds__(256)
void gemm_bt(const bf16_t* __restrict__ Ab, const bf16_t* __restrict__ Bb,
             bf16_t* __restrict__ Cb, int K, int ldc, int gx, int gy,
             long batchA, long batchB, long batchC,
             const float* __restrict__ bias, const float* __restrict__ aux_f,
             const bf16_t* __restrict__ resid, float* __restrict__ logits,
             const float* __restrict__ bias3)
{
    constexpr int SMEM_ELEMS = (EPI == 4) ? 32768 : 16384;   // 64 KB : 32 KB
    __shared__ __align__(16) bf16_t smem[SMEM_ELEMS];  // K-loop: As|Bs ; epilogue: C tile
    bf16_t* As = smem;                 // [128][64]
    bf16_t* Bs = smem + 8192;          // [128][64]

    const int tid  = threadIdx.x;
    const int lane = tid & 63;
    const int wave = tid >> 6;

    // --- block swizzle: XCD-contiguous + 4x4 supertiles ---
    const int flat = blockIdx.x;
    const int nb   = gridDim.x;                    // multiple of 8
    const int vid  = (flat & 7) * (nb >> 3) + (flat >> 3);
    const int pb   = gx * gy;                      // blocks per batch
    const int z    = vid / pb;
    const int w    = vid - z * pb;
    const int sy   = w / (gx * 4);
    const int r    = w - sy * (gx * 4);
    const int sx   = r >> 4;
    const int inner= r & 15;
    const int mtile = (sy * 4 + (inner & 3)) * 128;
    const int ntile = (sx * 4 + (inner >> 2)) * 128;

    const bf16_t* A  = Ab + (long)z * batchA;
    const bf16_t* Bp = Bb + (long)z * batchB;

    f32x4 acc[4][4];
    #pragma unroll
    for (int i = 0; i < 4; ++i)
        #pragma unroll
        for (int j = 0; j < 4; ++j)
            acc[i][j] = (f32x4)(0.f);

    const int lr  = lane & 15;         // fragment row-in-tile
    const int lr7 = lr & 7;
    const int lq  = lane >> 4;         // quad 0..3

    const int wrow = (wave >> 1) * 64;
    const int wcol = (wave & 1) * 64;

    // staging: one async16 call covers 8 rows (8 lanes/row, 16 B each)
    const int srow8 = lane >> 3;                       // 0..7
    const int sk    = ((lane & 7) ^ srow8) * 8;        // swizzled logical k-off

    for (int k0 = 0; k0 < K; k0 += 64) {
        __syncthreads();               // previous iter's LDS reads done
        #pragma unroll
        for (int j = 0; j < 4; ++j) {
            const int g   = (wave << 2) + j;          // 0..15, 8 rows each
            const int row = (g << 3) + srow8;         // 0..127
            async16(A  + (long)(mtile + row) * K + (k0 + sk), &As[g << 9]);
            async16(Bp + (long)(ntile + row) * K + (k0 + sk), &Bs[g << 9]);
        }
        __syncthreads();               // drains vmcnt (global_load_lds) too

        #pragma unroll
        for (int s = 0; s < 2; ++s) {  // two k-substeps of 32
            const int po = ((lq + (s << 2)) ^ lr7) << 3;   // phys 16B chunk
            bf16x8 af[4], bf[4];
            #pragma unroll
            for (int t = 0; t < 4; ++t)
                af[t] = *(const bf16x8*)&As[(wrow + t*16 + lr)*64 + po];
            #pragma unroll
            for (int t = 0; t < 4; ++t)
                bf[t] = *(const bf16x8*)&Bs[(wcol + t*16 + lr)*64 + po];
            #pragma unroll
            for (int tr = 0; tr < 4; ++tr)
                #pragma unroll
                for (int tc = 0; tc < 4; ++tc)
                    acc[tr][tc] = __builtin_amdgcn_mfma_f32_16x16x32_bf16(
                                      af[tr], bf[tc], acc[tr][tc], 0, 0, 0);
        }
    }

    // C/D layout: n = lane&15, m = (lane>>4)*4 + reg  [m89-verified]
    if constexpr (EPI == 5) {
        const int mbase = mtile + wrow + lq*4;
        #pragma unroll
        for (int tr = 0; tr < 4; ++tr) {
            #pragma unroll
            for (int reg = 0; reg < 4; ++reg) {
                const int m = mbase + tr*16 + reg;
                float rs = 0.f;
                #pragma unroll
                for (int tc = 0; tc < 4; ++tc) {
                    const int n = ntile + wcol + tc*16 + lr;
                    rs += tanhf(acc[tr][tc][reg]) * aux_f[n];
                }
                rs += __shfl_xor(rs, 1);
                rs += __shfl_xor(rs, 2);
                rs += __shfl_xor(rs, 4);
                rs += __shfl_xor(rs, 8);
                if (lr == 0) atomicAdd(&logits[m], rs);
            }
        }
        return;
    }

    // ---- staged epilogue ----
    __syncthreads();                   // all waves done reading As/Bs

    if constexpr (EPI == 4) {
        // fp32 LDS staging (64 KB): single bf16 rounding of h = Z + x.
        float* fsm = (float*)smem;     // [128][128] fp32
        #pragma unroll
        for (int tr = 0; tr < 4; ++tr) {
            #pragma unroll
            for (int reg = 0; reg < 4; ++reg) {
                const int rl = wrow + tr*16 + lq*4 + reg;
                #pragma unroll
                for (int tc = 0; tc < 4; ++tc) {
                    const int cl = wcol + tc*16 + lr;
                    fsm[rl*128 + ((((cl >> 2) ^ (rl & 31)) << 2) | (cl & 3))] = acc[tr][tc][reg];
                }
            }
        }
        __syncthreads();
        bf16_t* C = Cb + (long)z * batchC;
        const int chunk = tid & 15;    // 8 consecutive cols
        const int grp   = tid >> 4;
        #pragma unroll
        for (int rep = 0; rep < 8; ++rep) {
            const int R  = grp + rep*16;
            const int c0 = chunk*8;
            const int p0 = (((c0 >> 2)       ^ (R & 31)) << 2);
            const int p1 = ((((c0 + 4) >> 2) ^ (R & 31)) << 2);
            const f32x4 f0 = *(const f32x4*)&fsm[R*128 + p0];
            const f32x4 f1 = *(const f32x4*)&fsm[R*128 + p1];
            const long off = (long)(mtile + R)*ldc + ntile + c0;
            const bf16x8 r8 = *(const bf16x8*)&resid[(long)z*batchC + off];
            bf16x8 val;
            #pragma unroll
            for (int i = 0; i < 4; ++i) {
                val[i]     = (bf16_t)(f0[i] + (float)r8[i]);
                val[i + 4] = (bf16_t)(f1[i] + (float)r8[i + 4]);
            }
            *(bf16x8*)&C[off] = val;
        }
        return;
    }

    const int seg = (EPI == 6) ? (ntile >> 10) : 0;
    const float* bp = bias;
    if constexpr (EPI == 6) bp = (seg == 0) ? bias : (seg == 1) ? aux_f : bias3;

    // stage 1: registers -> LDS bf16 (col-chunk XOR row&7 swizzle -> ~2-way, free)
    #pragma unroll
    for (int tr = 0; tr < 4; ++tr) {
        #pragma unroll
        for (int reg = 0; reg < 4; ++reg) {
            const int rl = wrow + tr*16 + lq*4 + reg;        // 0..127
            #pragma unroll
            for (int tc = 0; tc < 4; ++tc) {
                const int cl = wcol + tc*16 + lr;            // 0..127
                float v = acc[tr][tc][reg];
                if constexpr (EPI == 0)
                    v += bias[ntile + cl] + aux_f[((mtile + rl) & (SEQ-1))*DMODEL + ntile + cl];
                if constexpr (EPI == 3) v *= 0.03125f;       // 1/sqrt(1024)
                if constexpr (EPI == 6) v += bp[(ntile + cl) & 1023];
                smem[rl*128 + ((((cl >> 3) ^ (rl & 7)) << 3) | (cl & 7))] = (bf16_t)v;
            }
        }
    }
    __syncthreads();

    // stage 2: LDS -> global, coalesced
    if constexpr (EPI == 6) {
        if (seg == 2) {
            // V transposed: VT[b][n][s]; contiguous dim = s = m
            bf16_t* VTb = Cb + 33554432;                     // Qb + 32M elems (64 MB)
            const int col  = tid & 127;                      // n_local within tile
            const int half = tid >> 7;
            const int b    = mtile >> 11, s0 = mtile & (SEQ-1);
            const long nbase = (long)b*DMODEL + (ntile & 1023) + col;
            #pragma unroll
            for (int rep = 0; rep < 8; ++rep) {
                const int R0 = half*64 + rep*8;
                bf16x8 o;
                #pragma unroll
                for (int i = 0; i < 8; ++i) {
                    const int rl = R0 + i;
                    o[i] = smem[rl*128 + ((((col >> 3) ^ (rl & 7)) << 3) | (col & 7))];
                }
                *(bf16x8*)&VTb[nbase*SEQ + s0 + R0] = o;
            }
            return;
        }
        const int chunk = tid & 15;
        const int grp   = tid >> 4;
        const long base = (long)seg * 16777216 + (ntile & 1023) + chunk*8;
        #pragma unroll
        for (int rep = 0; rep < 8; ++rep) {
            const int R = grp + rep*16;
            const int phys = chunk ^ (R & 7);
            bf16x8 val = *(const bf16x8*)&smem[R*128 + phys*8];
            *(bf16x8*)&Cb[base + (long)(mtile + R)*1024] = val;
        }
        return;
    }

    bf16_t* C = Cb + (long)z * batchC;
    const int chunk = tid & 15;
    const int grp   = tid >> 4;
    #pragma unroll
    for (int rep = 0; rep < 8; ++rep) {
        const int R = grp + rep*16;
        const int phys = chunk ^ (R & 7);
        bf16x8 val = *(const bf16x8*)&smem[R*128 + phys*8];
        const long off = (long)(mtile + R)*ldc + ntile + chunk*8;
        *(bf16x8*)&C[off] = val;
    }
}

// ---------------------------------------------------------------------------
__global__ void cast_f32_bf16(const float* __restrict__ s, bf16_t* __restrict__ d, int n4) {
    int i = blockIdx.x*256 + threadIdx.x;
    if (i < n4) {
        const float4 f = ((const float4*)s)[i];
        bf16x4 o;
        o.x = (bf16_t)f.x; o.y = (bf16_t)f.y; o.z = (bf16_t)f.z; o.w = (bf16_t)f.w;
        ((bf16x4*)d)[i] = o;
    }
}

__global__ void zero_f32_k(float* __restrict__ p, int n) {
    int i = blockIdx.x*256 + threadIdx.x;
    if (i < n) p[i] = 0.f;
}

// row softmax over 2048 bf16, in place; one block per row
__global__ __launch_bounds__(256) void softmax_rows_bf16(bf16_t* __restrict__ P) {
    bf16_t* row = P + (long)blockIdx.x * SEQ;
    const int t = threadIdx.x, lane = t & 63, wave = t >> 6;
    __shared__ float sm[8];
    float v[8]; float mx = -3.0e38f;
    #pragma unroll
    for (int j = 0; j < 8; ++j) { v[j] = (float)row[t + 256*j]; mx = fmaxf(mx, v[j]); }
    #pragma unroll
    for (int o = 32; o; o >>= 1) mx = fmaxf(mx, __shfl_xor(mx, o));
    if (lane == 0) sm[wave] = mx;
    __syncthreads();
    mx = fmaxf(fmaxf(sm[0], sm[1]), fmaxf(sm[2], sm[3]));
    float s = 0.f;
    #pragma unroll
    for (int j = 0; j < 8; ++j) { v[j] = __expf(v[j] - mx); s += v[j]; }
    #pragma unroll
    for (int o = 32; o; o >>= 1) s += __shfl_xor(s, o);
    if (lane == 0) sm[4 + wave] = s;
    __syncthreads();
    s = (sm[4] + sm[5]) + (sm[6] + sm[7]);
    const float inv = 1.f / s;
    #pragma unroll
    for (int j = 0; j < 8; ++j) row[t + 256*j] = (bf16_t)(v[j] * inv);
}

// per-batch softmax over 2048 fp32 logits
__global__ __launch_bounds__(256) void softmax_vec(const float* __restrict__ L, float* __restrict__ W) {
    const float* l = L + (long)blockIdx.x * SEQ;
    float* w = W + (long)blockIdx.x * SEQ;
    const int t = threadIdx.x, lane = t & 63, wave = t >> 6;
    __shared__ float sm[8];
    float v[8]; float mx = -3.0e38f;
    #pragma unroll
    for (int j = 0; j < 8; ++j) { v[j] = l[t + 256*j]; mx = fmaxf(mx, v[j]); }
    #pragma unroll
    for (int o = 32; o; o >>= 1) mx = fmaxf(mx, __shfl_xor(mx, o));
    if (lane == 0) sm[wave] = mx;
    __syncthreads();
    mx = fmaxf(fmaxf(sm[0], sm[1]), fmaxf(sm[2], sm[3]));
    float s = 0.f;
    #pragma unroll
    for (int j = 0; j < 8; ++j) { v[j] = __expf(v[j] - mx); s += v[j]; }
    #pragma unroll
    for (int o = 32; o; o >>= 1) s += __shfl_xor(s, o);
    if (lane == 0) sm[4 + wave] = s;
    __syncthreads();
    s = (sm[4] + sm[5]) + (sm[6] + sm[7]);
    const float inv = 1.f / s;
    #pragma unroll
    for (int j = 0; j < 8; ++j) w[t + 256*j] = v[j] * inv;
}

// LayerNorm over 1024: one block per row, h bf16 -> H bf16
__global__ __launch_bounds__(256) void layernorm_k(const bf16_t* __restrict__ h, bf16_t* __restrict__ H,
                                                   const float* __restrict__ gam, const float* __restrict__ bet) {
    const long row = blockIdx.x;
    const bf16_t* hr = h + row*DMODEL;
    bf16_t* Hr = H + row*DMODEL;
    const int t = threadIdx.x, lane = t & 63, wave = t >> 6;
    __shared__ float sm[8];
    float v[4]; float s = 0.f, q = 0.f;
    #pragma unroll
    for (int j = 0; j < 4; ++j) { v[j] = (float)hr[t + 256*j]; s += v[j]; q += v[j]*v[j]; }
    #pragma unroll
    for (int o = 32; o; o >>= 1) { s += __shfl_xor(s, o); q += __shfl_xor(q, o); }
    if (lane == 0) { sm[wave] = s; sm[4 + wave] = q; }
    __syncthreads();
    s = (sm[0] + sm[1]) + (sm[2] + sm[3]);
    q = (sm[4] + sm[5]) + (sm[6] + sm[7]);
    const float mu  = s * (1.f/DMODEL);
    const float var = q * (1.f/DMODEL) - mu*mu;
    const float r   = rsqrtf(var + 1e-5f);
    #pragma unroll
    for (int j = 0; j < 4; ++j) {
        const int n = t + 256*j;
        Hr[n] = (bf16_t)((v[j] - mu)*r*gam[n] + bet[n]);
    }
}

// ---------------------------------------------------------------------------
// Final pooling, stage 1: part[b][c][o] = sum_{s in chunk c} w[b][s]*H[b][s][o]
__global__ __launch_bounds__(256) void pool_partial(const float* __restrict__ w,
                                                    const bf16_t* __restrict__ H,
                                                    float* __restrict__ part) {
    const int b = blockIdx.y;
    const int c = blockIdx.x;
    const int t = threadIdx.x;
    const bf16_t* Hb = H + ((long)b*SEQ + (long)c*32)*DMODEL;
    const float*  wb = w + b*SEQ + c*32;
    f32x4 s = (f32x4)(0.f);
    #pragma unroll 4
    for (int i = 0; i < 32; ++i) {
        const float wi = wb[i];
        const bf16x4 hv = *(const bf16x4*)&Hb[(long)i*DMODEL + t*4];
        s[0] += wi * (float)hv[0];
        s[1] += wi * (float)hv[1];
        s[2] += wi * (float)hv[2];
        s[3] += wi * (float)hv[3];
    }
    *(f32x4*)&part[((long)b*64 + c)*DMODEL + t*4] = s;
}

// stage 2: out[b][o] = sum_c part[b][c][o]; 8192 threads
__global__ __launch_bounds__(256) void pool_reduce(const float* __restrict__ part,
                                                   float* __restrict__ out) {
    const int i = blockIdx.x*256 + threadIdx.x;   // 0..8191
    const int b = i >> 10, o = i & 1023;
    const float* p = part + (long)b*64*DMODEL + o;
    float s = 0.f;
    #pragma unroll
    for (int c = 0; c < 64; ++c) s += p[c*DMODEL];
    out[i] = s;
}

// ---------------------------------------------------------------------------
extern "C" void kernel_launch(void* const* d_in, const int* in_sizes, int n_in,
                              void* d_out, int out_size, void* d_ws, size_t ws_size,
                              hipStream_t stream) {
    (void)in_sizes; (void)n_in; (void)out_size; (void)ws_size;
    const float* inp = (const float*)d_in[0];
    const float* emw = (const float*)d_in[1];
    const float* emb = (const float*)d_in[2];
    const float* wqw = (const float*)d_in[3];
    const float* wqb = (const float*)d_in[4];
    const float* wkw = (const float*)d_in[5];
    const float* wkb = (const float*)d_in[6];
    const float* wvw = (const float*)d_in[7];
    const float* wvb = (const float*)d_in[8];
    const float* lng = (const float*)d_in[9];
    const float* lnb = (const float*)d_in[10];
    const float* skw = (const float*)d_in[11];
    const float* sq  = (const float*)d_in[12];
    const float* pos = (const float*)d_in[13];
    float* out = (float*)d_out;

    char* ws = (char*)d_ws;
    bf16_t* in_b   = (bf16_t*)(ws + 0);            // 16 MB (dead after embed; reused by pool partials)
    bf16_t* we_b   = (bf16_t*)(ws + 16777216);     // 1 MB
    bf16_t* wq_b   = (bf16_t*)(ws + 17825792);     // 2 MB  } contiguous [3072][1024]
    bf16_t* wk_b   = (bf16_t*)(ws + 19922944);     // 2 MB  }
    bf16_t* wv_b   = (bf16_t*)(ws + 22020096);     // 2 MB  }
    bf16_t* sk_b   = (bf16_t*)(ws + 24117248);     // 2 MB
    float*  logits = (float*)(ws + 26214400);      // 64 KB
    float*  wsoft  = (float*)(ws + 26279936);      // 64 KB
    bf16_t* xb     = (bf16_t*)(ws + 26345472);     // 32 MB  x (bf16)
    bf16_t* Qb     = (bf16_t*)(ws + 59899904);     // 32 MB  Q, later h   } Q|K|VT contiguous
    bf16_t* Kb     = (bf16_t*)(ws + 93454336);     // 32 MB               }
    bf16_t* VT     = (bf16_t*)(ws + 127008768);    // 32 MB  V^T [b][1024][2048]
    bf16_t* Hb     = (bf16_t*)(ws + 160563200);    // 32 MB
    bf16_t* Pb     = (bf16_t*)(ws + 194117632);    // 64 MB  scores/probs
    float*  part   = (float*)(ws + 0);             // 2 MB pool partials (aliases dead in_b)

    // casts fp32 -> bf16
    cast_f32_bf16<<<8192, 256, 0, stream>>>(inp, in_b, 2097152);
    cast_f32_bf16<<<512,  256, 0, stream>>>(emw, we_b, 131072);
    cast_f32_bf16<<<1024, 256, 0, stream>>>(wqw, wq_b, 262144);
    cast_f32_bf16<<<1024, 256, 0, stream>>>(wkw, wk_b, 262144);
    cast_f32_bf16<<<1024, 256, 0, stream>>>(wvw, wv_b, 262144);
    cast_f32_bf16<<<1024, 256, 0, stream>>>(skw, sk_b, 262144);
    zero_f32_k<<<64, 256, 0, stream>>>(logits, NTOK);

    // x = inputs @ embed_w^T + bias + pos       (gx=8 n-tiles, gy=128 m-tiles)
    gemm_bt<0><<<1024, 256, 0, stream>>>(in_b, we_b, xb, D_IN, DMODEL, 8, 128,
        0, 0, 0, emb, pos, nullptr, nullptr, nullptr);
    // fused QKV: N=3072 over contiguous weights; writes Q | K | VT
    gemm_bt<6><<<3072, 256, 0, stream>>>(xb, wq_b, Qb, DMODEL, DMODEL, 24, 128,
        0, 0, 0, wqb, wkb, nullptr, nullptr, wvb);
    // S = Q K^T / 32 (per batch), bf16          (one full batch per XCD)
    gemm_bt<3><<<2048, 256, 0, stream>>>(Qb, Kb, Pb, DMODEL, SEQ, 16, 16,
        (long)SEQ*DMODEL, (long)SEQ*DMODEL, (long)SEQ*SEQ, nullptr, nullptr, nullptr, nullptr, nullptr);
    softmax_rows_bf16<<<NTOK, 256, 0, stream>>>(Pb);
    // h = P V + x  (written over Q buffer)      (one full batch per XCD)
    gemm_bt<4><<<1024, 256, 0, stream>>>(Pb, VT, Qb, SEQ, DMODEL, 8, 16,
        (long)SEQ*SEQ, (long)DMODEL*SEQ, (long)SEQ*DMODEL, nullptr, nullptr, xb, nullptr, nullptr);
    layernorm_k<<<NTOK, 256, 0, stream>>>(Qb, Hb, lng, lnb);
    // logits[m] = sum_n tanh(H skw^T) * soft_query[n]
    gemm_bt<5><<<1024, 256, 0, stream>>>(Hb, sk_b, nullptr, DMODEL, 0, 8, 128,
        0, 0, 0, nullptr, sq, nullptr, logits, nullptr);
    softmax_vec<<<BATCH, 256, 0, stream>>>(logits, wsoft);
    // pooled output: two-stage parallel reduction
    pool_partial<<<dim3(64, BATCH), 256, 0, stream>>>(wsoft, Hb, part);
    pool_reduce<<<32, 256, 0, stream>>>(part, out);
}

// Round 7
// 519.140 us; speedup vs baseline: 1.8284x; 1.0641x over previous
//
#include <hip/hip_runtime.h>
#include <hip/hip_bf16.h>
#include <math.h>

typedef __bf16 bf16_t;
typedef bf16_t bf16x8 __attribute__((ext_vector_type(8)));
typedef bf16_t bf16x4 __attribute__((ext_vector_type(4)));
typedef float  f32x4  __attribute__((ext_vector_type(4)));

#define D_IN   512
#define DMODEL 1024
#define SEQ    2048
#define BATCH  8
#define NTOK   (BATCH*SEQ)

typedef __attribute__((address_space(1))) unsigned int gu32;
typedef __attribute__((address_space(3))) unsigned int lu32;

__device__ __forceinline__ void async16(const void* g, void* l) {
    __builtin_amdgcn_global_load_lds((gu32*)g, (lu32*)l, 16, 0, 0);
}

// ---------------------------------------------------------------------------
// Unified bf16 GEMM: C[M,N] = A[M,K] * B[N,K]^T   (both row-major over K)
// 128x128 block tile, 4 waves, each 64x64 (4x4 of 16x16x32 MFMA).
// R7: ping-pong double-buffered BK=64 K-loop, ONE barrier per iter:
//   barrier -> stage(k+1 into buf^1) -> compute(buf).
// The compiler's vmcnt(0) drain at the NEXT barrier now waits on loads that
// had a full compute phase (~620 CU-cyc of MFMA) to land — hides L2/HBM
// latency inside the block (R6 showed ~1.7 blocks/CU: too thin for implicit
// inter-wave overlap; the old issue->barrier->compute exposed full latency).
// LDS 64 KB (2x 32KB buffers); swizzle: 16B chunk phys = logical ^ (row&7),
// conflict-free for both async16 staging and ds_read_b128 (R6, verified 0).
// 1D grid; XCD-contiguous remap + 4x4 supertiles for L2 locality (R3).
// Epilogue: acc -> LDS tile -> coalesced bf16x8 stores (R4); EPI=4 stages in
// fp32 (64 KB) so h = bf16(Z_f32 + x) rounds ONCE (R5 numerics fix).
// EPI: 0 = +bias[n] + pos_enc[m%SEQ][n]                     (embed)
//      3 = *1/32                                            (scores)
//      4 = +resid[m][n] (fp32 staging)                      (P*V + x -> h)
//      5 = logits[m] += sum_n tanh(C)*sq[n], no C write     (soft_key)
//      6 = fused QKV: N=3072; seg=ntile>>10 -> Q | K | V^T  (+ per-seg bias)
// ---------------------------------------------------------------------------
template<int EPI>
__global__ __launch_bounds__(256)
void gemm_bt(const bf16_t* __restrict__ Ab, const bf16_t* __restrict__ Bb,
             bf16_t* __restrict__ Cb, int K, int ldc, int gx, int gy,
             long batchA, long batchB, long batchC,
             const float* __restrict__ bias, const float* __restrict__ aux_f,
             const bf16_t* __restrict__ resid, float* __restrict__ logits,
             const float* __restrict__ bias3)
{
    __shared__ __align__(16) bf16_t smem[32768];   // 64 KB: 2x(As|Bs); epilogue C tile

    const int tid  = threadIdx.x;
    const int lane = tid & 63;
    const int wave = tid >> 6;

    // --- block swizzle: XCD-contiguous + 4x4 supertiles ---
    const int flat = blockIdx.x;
    const int nb   = gridDim.x;                    // multiple of 8
    const int vid  = (flat & 7) * (nb >> 3) + (flat >> 3);
    const int pb   = gx * gy;                      // blocks per batch
    const int z    = vid / pb;
    const int w    = vid - z * pb;
    const int sy   = w / (gx * 4);
    const int r    = w - sy * (gx * 4);
    const int sx   = r >> 4;
    const int inner= r & 15;
    const int mtile = (sy * 4 + (inner & 3)) * 128;
    const int ntile = (sx * 4 + (inner >> 2)) * 128;

    const bf16_t* A  = Ab + (long)z * batchA;
    const bf16_t* Bp = Bb + (long)z * batchB;

    f32x4 acc[4][4];
    #pragma unroll
    for (int i = 0; i < 4; ++i)
        #pragma unroll
        for (int j = 0; j < 4; ++j)
            acc[i][j] = (f32x4)(0.f);

    const int lr  = lane & 15;         // fragment row-in-tile
    const int lr7 = lr & 7;
    const int lq  = lane >> 4;         // quad 0..3

    const int wrow = (wave >> 1) * 64;
    const int wcol = (wave & 1) * 64;

    // staging: one async16 covers 8 rows (8 lanes/row, 16 B each)
    const int srow8 = lane >> 3;                       // 0..7
    const int sk    = ((lane & 7) ^ srow8) * 8;        // swizzled logical k-off

    // prefetch tile 0 into buffer 0
    {
        bf16_t* Ad = smem;
        bf16_t* Bd = smem + 8192;
        #pragma unroll
        for (int j = 0; j < 4; ++j) {
            const int g   = (wave << 2) + j;
            const int row = (g << 3) + srow8;
            async16(A  + (long)(mtile + row) * K + sk, &Ad[g << 9]);
            async16(Bp + (long)(ntile + row) * K + sk, &Bd[g << 9]);
        }
    }

    int cur = 0;
    for (int k0 = 0; k0 < K; k0 += 64) {
        __syncthreads();               // our prefetch landed (vmcnt0 drain); prev reads done
        if (k0 + 64 < K) {             // stage NEXT tile into the other buffer
            bf16_t* Ad = smem + ((cur ^ 1) << 14);
            bf16_t* Bd = Ad + 8192;
            const int kn = k0 + 64;
            #pragma unroll
            for (int j = 0; j < 4; ++j) {
                const int g   = (wave << 2) + j;
                const int row = (g << 3) + srow8;
                async16(A  + (long)(mtile + row) * K + (kn + sk), &Ad[g << 9]);
                async16(Bp + (long)(ntile + row) * K + (kn + sk), &Bd[g << 9]);
            }
        }
        const bf16_t* Ar = smem + (cur << 14);
        const bf16_t* Br = Ar + 8192;
        #pragma unroll
        for (int s = 0; s < 2; ++s) {  // two k-substeps of 32
            const int po = ((lq + (s << 2)) ^ lr7) << 3;   // phys 16B chunk
            bf16x8 af[4], bf[4];
            #pragma unroll
            for (int t = 0; t < 4; ++t)
                af[t] = *(const bf16x8*)&Ar[(wrow + t*16 + lr)*64 + po];
            #pragma unroll
            for (int t = 0; t < 4; ++t)
                bf[t] = *(const bf16x8*)&Br[(wcol + t*16 + lr)*64 + po];
            #pragma unroll
            for (int tr = 0; tr < 4; ++tr)
                #pragma unroll
                for (int tc = 0; tc < 4; ++tc)
                    acc[tr][tc] = __builtin_amdgcn_mfma_f32_16x16x32_bf16(
                                      af[tr], bf[tc], acc[tr][tc], 0, 0, 0);
        }
        cur ^= 1;
    }

    // C/D layout: n = lane&15, m = (lane>>4)*4 + reg  [m89-verified]
    if constexpr (EPI == 5) {
        const int mbase = mtile + wrow + lq*4;
        #pragma unroll
        for (int tr = 0; tr < 4; ++tr) {
            #pragma unroll
            for (int reg = 0; reg < 4; ++reg) {
                const int m = mbase + tr*16 + reg;
                float rs = 0.f;
                #pragma unroll
                for (int tc = 0; tc < 4; ++tc) {
                    const int n = ntile + wcol + tc*16 + lr;
                    rs += tanhf(acc[tr][tc][reg]) * aux_f[n];
                }
                rs += __shfl_xor(rs, 1);
                rs += __shfl_xor(rs, 2);
                rs += __shfl_xor(rs, 4);
                rs += __shfl_xor(rs, 8);
                if (lr == 0) atomicAdd(&logits[m], rs);
            }
        }
        return;
    }

    // ---- staged epilogue ----
    __syncthreads();                   // all waves done reading K-loop LDS

    if constexpr (EPI == 4) {
        // fp32 LDS staging (64 KB): single bf16 rounding of h = Z + x.
        float* fsm = (float*)smem;     // [128][128] fp32
        #pragma unroll
        for (int tr = 0; tr < 4; ++tr) {
            #pragma unroll
            for (int reg = 0; reg < 4; ++reg) {
                const int rl = wrow + tr*16 + lq*4 + reg;
                #pragma unroll
                for (int tc = 0; tc < 4; ++tc) {
                    const int cl = wcol + tc*16 + lr;
                    fsm[rl*128 + ((((cl >> 2) ^ (rl & 31)) << 2) | (cl & 3))] = acc[tr][tc][reg];
                }
            }
        }
        __syncthreads();
        bf16_t* C = Cb + (long)z * batchC;
        const int chunk = tid & 15;    // 8 consecutive cols
        const int grp   = tid >> 4;
        #pragma unroll
        for (int rep = 0; rep < 8; ++rep) {
            const int R  = grp + rep*16;
            const int c0 = chunk*8;
            const int p0 = (((c0 >> 2)       ^ (R & 31)) << 2);
            const int p1 = ((((c0 + 4) >> 2) ^ (R & 31)) << 2);
            const f32x4 f0 = *(const f32x4*)&fsm[R*128 + p0];
            const f32x4 f1 = *(const f32x4*)&fsm[R*128 + p1];
            const long off = (long)(mtile + R)*ldc + ntile + c0;
            const bf16x8 r8 = *(const bf16x8*)&resid[(long)z*batchC + off];
            bf16x8 val;
            #pragma unroll
            for (int i = 0; i < 4; ++i) {
                val[i]     = (bf16_t)(f0[i] + (float)r8[i]);
                val[i + 4] = (bf16_t)(f1[i] + (float)r8[i + 4]);
            }
            *(bf16x8*)&C[off] = val;
        }
        return;
    }

    const int seg = (EPI == 6) ? (ntile >> 10) : 0;
    const float* bp = bias;
    if constexpr (EPI == 6) bp = (seg == 0) ? bias : (seg == 1) ? aux_f : bias3;

    // stage 1: registers -> LDS bf16 (col-chunk XOR row&7 swizzle -> ~2-way, free)
    #pragma unroll
    for (int tr = 0; tr < 4; ++tr) {
        #pragma unroll
        for (int reg = 0; reg < 4; ++reg) {
            const int rl = wrow + tr*16 + lq*4 + reg;        // 0..127
            #pragma unroll
            for (int tc = 0; tc < 4; ++tc) {
                const int cl = wcol + tc*16 + lr;            // 0..127
                float v = acc[tr][tc][reg];
                if constexpr (EPI == 0)
                    v += bias[ntile + cl] + aux_f[((mtile + rl) & (SEQ-1))*DMODEL + ntile + cl];
                if constexpr (EPI == 3) v *= 0.03125f;       // 1/sqrt(1024)
                if constexpr (EPI == 6) v += bp[(ntile + cl) & 1023];
                smem[rl*128 + ((((cl >> 3) ^ (rl & 7)) << 3) | (cl & 7))] = (bf16_t)v;
            }
        }
    }
    __syncthreads();

    // stage 2: LDS -> global, coalesced
    if constexpr (EPI == 6) {
        if (seg == 2) {
            // V transposed: VT[b][n][s]; contiguous dim = s = m
            bf16_t* VTb = Cb + 33554432;                     // Qb + 32M elems (64 MB)
            const int col  = tid & 127;                      // n_local within tile
            const int half = tid >> 7;
            const int b    = mtile >> 11, s0 = mtile & (SEQ-1);
            const long nbase = (long)b*DMODEL + (ntile & 1023) + col;
            #pragma unroll
            for (int rep = 0; rep < 8; ++rep) {
                const int R0 = half*64 + rep*8;
                bf16x8 o;
                #pragma unroll
                for (int i = 0; i < 8; ++i) {
                    const int rl = R0 + i;
                    o[i] = smem[rl*128 + ((((col >> 3) ^ (rl & 7)) << 3) | (col & 7))];
                }
                *(bf16x8*)&VTb[nbase*SEQ + s0 + R0] = o;
            }
            return;
        }
        const int chunk = tid & 15;
        const int grp   = tid >> 4;
        const long base = (long)seg * 16777216 + (ntile & 1023) + chunk*8;
        #pragma unroll
        for (int rep = 0; rep < 8; ++rep) {
            const int R = grp + rep*16;
            const int phys = chunk ^ (R & 7);
            bf16x8 val = *(const bf16x8*)&smem[R*128 + phys*8];
            *(bf16x8*)&Cb[base + (long)(mtile + R)*1024] = val;
        }
        return;
    }

    bf16_t* C = Cb + (long)z * batchC;
    const int chunk = tid & 15;
    const int grp   = tid >> 4;
    #pragma unroll
    for (int rep = 0; rep < 8; ++rep) {
        const int R = grp + rep*16;
        const int phys = chunk ^ (R & 7);
        bf16x8 val = *(const bf16x8*)&smem[R*128 + phys*8];
        const long off = (long)(mtile + R)*ldc + ntile + chunk*8;
        *(bf16x8*)&C[off] = val;
    }
}

// ---------------------------------------------------------------------------
__global__ void cast_f32_bf16(const float* __restrict__ s, bf16_t* __restrict__ d, int n4) {
    int i = blockIdx.x*256 + threadIdx.x;
    if (i < n4) {
        const float4 f = ((const float4*)s)[i];
        bf16x4 o;
        o.x = (bf16_t)f.x; o.y = (bf16_t)f.y; o.z = (bf16_t)f.z; o.w = (bf16_t)f.w;
        ((bf16x4*)d)[i] = o;
    }
}

__global__ void zero_f32_k(float* __restrict__ p, int n) {
    int i = blockIdx.x*256 + threadIdx.x;
    if (i < n) p[i] = 0.f;
}

// row softmax over 2048 bf16, in place; one block per row
__global__ __launch_bounds__(256) void softmax_rows_bf16(bf16_t* __restrict__ P) {
    bf16_t* row = P + (long)blockIdx.x * SEQ;
    const int t = threadIdx.x, lane = t & 63, wave = t >> 6;
    __shared__ float sm[8];
    float v[8]; float mx = -3.0e38f;
    #pragma unroll
    for (int j = 0; j < 8; ++j) { v[j] = (float)row[t + 256*j]; mx = fmaxf(mx, v[j]); }
    #pragma unroll
    for (int o = 32; o; o >>= 1) mx = fmaxf(mx, __shfl_xor(mx, o));
    if (lane == 0) sm[wave] = mx;
    __syncthreads();
    mx = fmaxf(fmaxf(sm[0], sm[1]), fmaxf(sm[2], sm[3]));
    float s = 0.f;
    #pragma unroll
    for (int j = 0; j < 8; ++j) { v[j] = __expf(v[j] - mx); s += v[j]; }
    #pragma unroll
    for (int o = 32; o; o >>= 1) s += __shfl_xor(s, o);
    if (lane == 0) sm[4 + wave] = s;
    __syncthreads();
    s = (sm[4] + sm[5]) + (sm[6] + sm[7]);
    const float inv = 1.f / s;
    #pragma unroll
    for (int j = 0; j < 8; ++j) row[t + 256*j] = (bf16_t)(v[j] * inv);
}

// per-batch softmax over 2048 fp32 logits
__global__ __launch_bounds__(256) void softmax_vec(const float* __restrict__ L, float* __restrict__ W) {
    const float* l = L + (long)blockIdx.x * SEQ;
    float* w = W + (long)blockIdx.x * SEQ;
    const int t = threadIdx.x, lane = t & 63, wave = t >> 6;
    __shared__ float sm[8];
    float v[8]; float mx = -3.0e38f;
    #pragma unroll
    for (int j = 0; j < 8; ++j) { v[j] = l[t + 256*j]; mx = fmaxf(mx, v[j]); }
    #pragma unroll
    for (int o = 32; o; o >>= 1) mx = fmaxf(mx, __shfl_xor(mx, o));
    if (lane == 0) sm[wave] = mx;
    __syncthreads();
    mx = fmaxf(fmaxf(sm[0], sm[1]), fmaxf(sm[2], sm[3]));
    float s = 0.f;
    #pragma unroll
    for (int j = 0; j < 8; ++j) { v[j] = __expf(v[j] - mx); s += v[j]; }
    #pragma unroll
    for (int o = 32; o; o >>= 1) s += __shfl_xor(s, o);
    if (lane == 0) sm[4 + wave] = s;
    __syncthreads();
    s = (sm[4] + sm[5]) + (sm[6] + sm[7]);
    const float inv = 1.f / s;
    #pragma unroll
    for (int j = 0; j < 8; ++j) w[t + 256*j] = v[j] * inv;
}

// LayerNorm over 1024: one block per row, h bf16 -> H bf16
__global__ __launch_bounds__(256) void layernorm_k(const bf16_t* __restrict__ h, bf16_t* __restrict__ H,
                                                   const float* __restrict__ gam, const float* __restrict__ bet) {
    const long row = blockIdx.x;
    const bf16_t* hr = h + row*DMODEL;
    bf16_t* Hr = H + row*DMODEL;
    const int t = threadIdx.x, lane = t & 63, wave = t >> 6;
    __shared__ float sm[8];
    float v[4]; float s = 0.f, q = 0.f;
    #pragma unroll
    for (int j = 0; j < 4; ++j) { v[j] = (float)hr[t + 256*j]; s += v[j]; q += v[j]*v[j]; }
    #pragma unroll
    for (int o = 32; o; o >>= 1) { s += __shfl_xor(s, o); q += __shfl_xor(q, o); }
    if (lane == 0) { sm[wave] = s; sm[4 + wave] = q; }
    __syncthreads();
    s = (sm[0] + sm[1]) + (sm[2] + sm[3]);
    q = (sm[4] + sm[5]) + (sm[6] + sm[7]);
    const float mu  = s * (1.f/DMODEL);
    const float var = q * (1.f/DMODEL) - mu*mu;
    const float r   = rsqrtf(var + 1e-5f);
    #pragma unroll
    for (int j = 0; j < 4; ++j) {
        const int n = t + 256*j;
        Hr[n] = (bf16_t)((v[j] - mu)*r*gam[n] + bet[n]);
    }
}

// ---------------------------------------------------------------------------
// Final pooling, stage 1: part[b][c][o] = sum_{s in chunk c} w[b][s]*H[b][s][o]
__global__ __launch_bounds__(256) void pool_partial(const float* __restrict__ w,
                                                    const bf16_t* __restrict__ H,
                                                    float* __restrict__ part) {
    const int b = blockIdx.y;
    const int c = blockIdx.x;
    const int t = threadIdx.x;
    const bf16_t* Hb = H + ((long)b*SEQ + (long)c*32)*DMODEL;
    const float*  wb = w + b*SEQ + c*32;
    f32x4 s = (f32x4)(0.f);
    #pragma unroll 4
    for (int i = 0; i < 32; ++i) {
        const float wi = wb[i];
        const bf16x4 hv = *(const bf16x4*)&Hb[(long)i*DMODEL + t*4];
        s[0] += wi * (float)hv[0];
        s[1] += wi * (float)hv[1];
        s[2] += wi * (float)hv[2];
        s[3] += wi * (float)hv[3];
    }
    *(f32x4*)&part[((long)b*64 + c)*DMODEL + t*4] = s;
}

// stage 2: out[b][o] = sum_c part[b][c][o]; 8192 threads
__global__ __launch_bounds__(256) void pool_reduce(const float* __restrict__ part,
                                                   float* __restrict__ out) {
    const int i = blockIdx.x*256 + threadIdx.x;   // 0..8191
    const int b = i >> 10, o = i & 1023;
    const float* p = part + (long)b*64*DMODEL + o;
    float s = 0.f;
    #pragma unroll
    for (int c = 0; c < 64; ++c) s += p[c*DMODEL];
    out[i] = s;
}

// ---------------------------------------------------------------------------
extern "C" void kernel_launch(void* const* d_in, const int* in_sizes, int n_in,
                              void* d_out, int out_size, void* d_ws, size_t ws_size,
                              hipStream_t stream) {
    (void)in_sizes; (void)n_in; (void)out_size; (void)ws_size;
    const float* inp = (const float*)d_in[0];
    const float* emw = (const float*)d_in[1];
    const float* emb = (const float*)d_in[2];
    const float* wqw = (const float*)d_in[3];
    const float* wqb = (const float*)d_in[4];
    const float* wkw = (const float*)d_in[5];
    const float* wkb = (const float*)d_in[6];
    const float* wvw = (const float*)d_in[7];
    const float* wvb = (const float*)d_in[8];
    const float* lng = (const float*)d_in[9];
    const float* lnb = (const float*)d_in[10];
    const float* skw = (const float*)d_in[11];
    const float* sq  = (const float*)d_in[12];
    const float* pos = (const float*)d_in[13];
    float* out = (float*)d_out;

    char* ws = (char*)d_ws;
    bf16_t* in_b   = (bf16_t*)(ws + 0);            // 16 MB (dead after embed; reused by pool partials)
    bf16_t* we_b   = (bf16_t*)(ws + 16777216);     // 1 MB
    bf16_t* wq_b   = (bf16_t*)(ws + 17825792);     // 2 MB  } contiguous [3072][1024]
    bf16_t* wk_b   = (bf16_t*)(ws + 19922944);     // 2 MB  }
    bf16_t* wv_b   = (bf16_t*)(ws + 22020096);     // 2 MB  }
    bf16_t* sk_b   = (bf16_t*)(ws + 24117248);     // 2 MB
    float*  logits = (float*)(ws + 26214400);      // 64 KB
    float*  wsoft  = (float*)(ws + 26279936);      // 64 KB
    bf16_t* xb     = (bf16_t*)(ws + 26345472);     // 32 MB  x (bf16)
    bf16_t* Qb     = (bf16_t*)(ws + 59899904);     // 32 MB  Q, later h   } Q|K|VT contiguous
    bf16_t* Kb     = (bf16_t*)(ws + 93454336);     // 32 MB               }
    bf16_t* VT     = (bf16_t*)(ws + 127008768);    // 32 MB  V^T [b][1024][2048]
    bf16_t* Hb     = (bf16_t*)(ws + 160563200);    // 32 MB
    bf16_t* Pb     = (bf16_t*)(ws + 194117632);    // 64 MB  scores/probs
    float*  part   = (float*)(ws + 0);             // 2 MB pool partials (aliases dead in_b)

    // casts fp32 -> bf16
    cast_f32_bf16<<<8192, 256, 0, stream>>>(inp, in_b, 2097152);
    cast_f32_bf16<<<512,  256, 0, stream>>>(emw, we_b, 131072);
    cast_f32_bf16<<<1024, 256, 0, stream>>>(wqw, wq_b, 262144);
    cast_f32_bf16<<<1024, 256, 0, stream>>>(wkw, wk_b, 262144);
    cast_f32_bf16<<<1024, 256, 0, stream>>>(wvw, wv_b, 262144);
    cast_f32_bf16<<<1024, 256, 0, stream>>>(skw, sk_b, 262144);
    zero_f32_k<<<64, 256, 0, stream>>>(logits, NTOK);

    // x = inputs @ embed_w^T + bias + pos       (gx=8 n-tiles, gy=128 m-tiles)
    gemm_bt<0><<<1024, 256, 0, stream>>>(in_b, we_b, xb, D_IN, DMODEL, 8, 128,
        0, 0, 0, emb, pos, nullptr, nullptr, nullptr);
    // fused QKV: N=3072 over contiguous weights; writes Q | K | VT
    gemm_bt<6><<<3072, 256, 0, stream>>>(xb, wq_b, Qb, DMODEL, DMODEL, 24, 128,
        0, 0, 0, wqb, wkb, nullptr, nullptr, wvb);
    // S = Q K^T / 32 (per batch), bf16          (one full batch per XCD)
    gemm_bt<3><<<2048, 256, 0, stream>>>(Qb, Kb, Pb, DMODEL, SEQ, 16, 16,
        (long)SEQ*DMODEL, (long)SEQ*DMODEL, (long)SEQ*SEQ, nullptr, nullptr, nullptr, nullptr, nullptr);
    softmax_rows_bf16<<<NTOK, 256, 0, stream>>>(Pb);
    // h = P V + x  (written over Q buffer)      (one full batch per XCD)
    gemm_bt<4><<<1024, 256, 0, stream>>>(Pb, VT, Qb, SEQ, DMODEL, 8, 16,
        (long)SEQ*SEQ, (long)DMODEL*SEQ, (long)SEQ*DMODEL, nullptr, nullptr, xb, nullptr, nullptr);
    layernorm_k<<<NTOK, 256, 0, stream>>>(Qb, Hb, lng, lnb);
    // logits[m] = sum_n tanh(H skw^T) * soft_query[n]
    gemm_bt<5><<<1024, 256, 0, stream>>>(Hb, sk_b, nullptr, DMODEL, 0, 8, 128,
        0, 0, 0, nullptr, sq, nullptr, logits, nullptr);
    softmax_vec<<<BATCH, 256, 0, stream>>>(logits, wsoft);
    // pooled output: two-stage parallel reduction
    pool_partial<<<dim3(64, BATCH), 256, 0, stream>>>(wsoft, Hb, part);
    pool_reduce<<<32, 256, 0, stream>>>(part, out);
}